// Round 5
// baseline (637.889 us; speedup 1.0000x reference)
//
#include <hip/hip_runtime.h>
#include <hip/hip_fp16.h>
#include <float.h>
#include <math.h>

#define HH 40
#define WW 128
#define PP 5120
#define NN 5120
#define CC 128
#define KK 25
#define SPOT 5
#define NEGV -1e8f

#define CSPL 8          // column segments for the MFMA screen
#define EPSG 2e-3f      // screen gap threshold >> fp16 worst-case dot err (5.2e-4)

typedef _Float16 half8 __attribute__((ext_vector_type(8)));
typedef float f32x4 __attribute__((ext_vector_type(4)));

// ---------------- K1: L2-normalize rows (fp64 norm; fp32 + fp16 copies) ----------
__global__ void k_normalize(const float* __restrict__ imf, const float* __restrict__ pcf,
                            float* __restrict__ imn, float* __restrict__ pcn,
                            __half* __restrict__ imh, __half* __restrict__ pch) {
    int row = blockIdx.x * 4 + (threadIdx.x >> 6);
    int lane = threadIdx.x & 63;
    const float* src; float* dst; __half* dsth; int r;
    if (row < PP) { src = imf; dst = imn; dsth = imh; r = row; }
    else          { src = pcf; dst = pcn; dsth = pch; r = row - PP; }
    float2 v = *(const float2*)&src[r * CC + lane * 2];
    double ss = (double)v.x * (double)v.x + (double)v.y * (double)v.y;
#pragma unroll
    for (int o = 32; o; o >>= 1) ss += __shfl_xor(ss, o);
    double inv = 1.0 / fmax(sqrt(ss), 1e-12);
    float2 o2 = make_float2((float)((double)v.x * inv), (float)((double)v.y * inv));
    *(float2*)&dst[r * CC + lane * 2] = o2;
    *(__half2*)&dsth[r * CC + lane * 2] = __floats2half2_rn(o2.x, o2.y);
}

// ---------------- K2: KNN top-25, register-tournament ----------------------------
__global__ __launch_bounds__(256) void k_knn(const float* __restrict__ pts,
                                             int* __restrict__ nb) {
    __shared__ double sv[2][4];
    __shared__ int    si[2][4];
    int i = blockIdx.x;
    int t = threadIdx.x;
    int wid = t >> 6, lane = t & 63;
    double px = pts[i * 3 + 0], py = pts[i * 3 + 1], pz = pts[i * 3 + 2];

    double d[20];
    int base = t * 20;
    double lv = DBL_MAX; int li = 0x7fffffff;
#pragma unroll
    for (int e = 0; e < 20; ++e) {
        int j = base + e;
        double dx = px - (double)pts[j * 3 + 0];
        double dy = py - (double)pts[j * 3 + 1];
        double dz = pz - (double)pts[j * 3 + 2];
        double v = dx * dx + dy * dy + dz * dz;
        d[e] = v;
        if (v < lv) { lv = v; li = j; }
    }

    unsigned removed = 0u;
    for (int it = 0; it < KK; ++it) {
        double bv = lv; int bi = li;
#pragma unroll
        for (int o = 32; o; o >>= 1) {
            double ov = __shfl_xor(bv, o); int oi = __shfl_xor(bi, o);
            if (ov < bv || (ov == bv && oi < bi)) { bv = ov; bi = oi; }
        }
        int par = it & 1;
        if (lane == 0) { sv[par][wid] = bv; si[par][wid] = bi; }
        __syncthreads();
        bv = sv[par][0]; bi = si[par][0];
#pragma unroll
        for (int wv = 1; wv < 4; ++wv) {
            double ov = sv[par][wv]; int oi = si[par][wv];
            if (ov < bv || (ov == bv && oi < bi)) { bv = ov; bi = oi; }
        }
        if (t == 0) nb[i * KK + it] = bi;
        if (bi >= base && bi < base + 20) {
            removed |= 1u << (bi - base);
            lv = DBL_MAX; li = 0x7fffffff;
#pragma unroll
            for (int e = 0; e < 20; ++e) {
                bool alive = !((removed >> e) & 1u);
                if (alive && d[e] < lv) { lv = d[e]; li = base + e; }
            }
        }
    }
}

// ---------------- K3: fp16 MFMA cosine screen: per-row (best, 2nd, argmax) -------
// blockIdx.z: 0 rows=im cols=pc, 1 rows=pc cols=im. Block tile 128 rows x 640 cols,
// 4 waves (2x2), per-wave 64x64 per 128-col chunk, K=128 complete.
// LDS [row][128 f16] with byte ^= ((row&7)<<4) swizzle: writes and b128 reads <=2-way.
// A/B frags use the identical (row, 8-contig-k) load pattern, so any k-permutation
// in the HW frag layout cancels between operands; C/D map (m89): row=(l>>4)*4+reg,
// col=l&15. Ties/near-ties (gap<EPSG) repaired exactly by k_recheck.
__global__ __launch_bounds__(256, 2) void k_rowmax(const __half* __restrict__ imh,
                                                   const __half* __restrict__ pch,
                                                   float* __restrict__ pval,
                                                   float* __restrict__ pv2,
                                                   int* __restrict__ pidx) {
    const __half* Ah = (blockIdx.z == 0) ? imh : pch;
    const __half* Bh = (blockIdx.z == 0) ? pch : imh;
    __shared__ char As[128 * 256];
    __shared__ char Bs[128 * 256];

    int t = threadIdx.x;
    int wave = t >> 6, l = t & 63;
    int wrow = wave >> 1, wcol = wave & 1;
    int lg = l >> 4, lc = l & 15;
    int rb = blockIdx.x * 128;
    int segbase = blockIdx.y * (NN / CSPL);

    // stage A once (reg-staged so dest can be swizzled)
#pragma unroll
    for (int i = 0; i < 8; ++i) {
        int u = t + i * 256;
        int row = u >> 4, kb = u & 15;
        uint4 v = *(const uint4*)&Ah[(size_t)(rb + row) * CC + kb * 8];
        *(uint4*)(As + row * 256 + ((kb * 16) ^ ((row & 7) << 4))) = v;
    }

    float v1[4][4], v2[4][4]; int i1[4][4];
#pragma unroll
    for (int rt = 0; rt < 4; ++rt)
#pragma unroll
        for (int rg = 0; rg < 4; ++rg) { v1[rt][rg] = -1e30f; v2[rt][rg] = -1e30f; i1[rt][rg] = 0; }

    for (int ch = 0; ch < NN / CSPL; ch += 128) {
#pragma unroll
        for (int i = 0; i < 8; ++i) {
            int u = t + i * 256;
            int row = u >> 4, kb = u & 15;
            uint4 v = *(const uint4*)&Bh[(size_t)(segbase + ch + row) * CC + kb * 8];
            *(uint4*)(Bs + row * 256 + ((kb * 16) ^ ((row & 7) << 4))) = v;
        }
        __syncthreads();

        f32x4 acc[4][4];
#pragma unroll
        for (int rt = 0; rt < 4; ++rt)
#pragma unroll
            for (int ct = 0; ct < 4; ++ct) acc[rt][ct] = (f32x4){0.f, 0.f, 0.f, 0.f};

#pragma unroll
        for (int ks = 0; ks < 4; ++ks) {
            int kb = ks * 64 + lg * 16;
            half8 a[4], b[4];
#pragma unroll
            for (int rt = 0; rt < 4; ++rt) {
                int row = wrow * 64 + rt * 16 + lc;
                a[rt] = *(const half8*)(As + row * 256 + (kb ^ ((row & 7) << 4)));
            }
#pragma unroll
            for (int ct = 0; ct < 4; ++ct) {
                int row = wcol * 64 + ct * 16 + lc;
                b[ct] = *(const half8*)(Bs + row * 256 + (kb ^ ((row & 7) << 4)));
            }
#pragma unroll
            for (int rt = 0; rt < 4; ++rt)
#pragma unroll
                for (int ct = 0; ct < 4; ++ct)
                    acc[rt][ct] = __builtin_amdgcn_mfma_f32_16x16x32_f16(
                        a[rt], b[ct], acc[rt][ct], 0, 0, 0);
        }

        int colb = segbase + ch + wcol * 64 + lc;
#pragma unroll
        for (int rt = 0; rt < 4; ++rt)
#pragma unroll
            for (int ct = 0; ct < 4; ++ct) {
                int c = colb + ct * 16;
#pragma unroll
                for (int rg = 0; rg < 4; ++rg) {
                    float v = acc[rt][ct][rg];
                    bool gt = v > v1[rt][rg];
                    v2[rt][rg] = gt ? v1[rt][rg] : fmaxf(v2[rt][rg], v);  // tie -> gap 0 -> recheck
                    i1[rt][rg] = gt ? c : i1[rt][rg];
                    v1[rt][rg] = gt ? v : v1[rt][rg];
                }
            }
        __syncthreads();
    }

    // merge top-2 across the 16 column lanes
#pragma unroll
    for (int rt = 0; rt < 4; ++rt)
#pragma unroll
        for (int rg = 0; rg < 4; ++rg) {
            float a1 = v1[rt][rg], a2 = v2[rt][rg]; int ai = i1[rt][rg];
#pragma unroll
            for (int o = 1; o < 16; o <<= 1) {
                float o1 = __shfl_xor(a1, o);
                float o2v = __shfl_xor(a2, o);
                int   oi = __shfl_xor(ai, o);
                if (o1 > a1) { a2 = fmaxf(a1, o2v); a1 = o1; ai = oi; }
                else         { a2 = fmaxf(a2, o1); }   // o1==a1 -> a2=a1 -> flagged
            }
            if (lc == 0) {
                size_t o = ((size_t)blockIdx.z * CSPL + blockIdx.y) * PP
                         + rb + wrow * 64 + rt * 16 + lg * 4 + rg;
                pval[o] = a1; pv2[o] = a2; pidx[o] = ai;
            }
        }
}

// ---------------- K3b: reduce split partials, flag ambiguous rows ----------------
__global__ void k_reduce_best(const float* __restrict__ pval, const float* __restrict__ pv2,
                              const int* __restrict__ pidx,
                              int* __restrict__ bestI, int* __restrict__ bestPI,
                              int* __restrict__ list, int* __restrict__ cnt) {
    int r = blockIdx.x * 256 + threadIdx.x;
    int side = blockIdx.y;
    size_t base = (size_t)side * CSPL * PP + r;
    float v1 = pval[base], v2 = pv2[base]; int i1 = pidx[base];
    for (int s = 1; s < CSPL; ++s) {
        float ov1 = pval[base + (size_t)s * PP];
        float ov2 = pv2[base + (size_t)s * PP];
        int   oi  = pidx[base + (size_t)s * PP];
        if (ov1 > v1) { v2 = fmaxf(v1, ov2); v1 = ov1; i1 = oi; }
        else          { v2 = fmaxf(v2, ov1); }
    }
    if (side == 0) bestI[r] = i1; else bestPI[r] = i1;
    if (v1 - v2 < EPSG) {
        int slot = atomicAdd(cnt, 1);
        list[slot] = r | (side << 16);
    }
}

// ---------------- K3c: exact fp64 best VALUE for every row (argmax from screen) --
__global__ void k_exact_best(const float* __restrict__ imn, const float* __restrict__ pcn,
                             const int* __restrict__ bestI, const int* __restrict__ bestPI,
                             double* __restrict__ bestSd, double* __restrict__ bestPSd) {
    int row = blockIdx.x * 4 + (threadIdx.x >> 6);
    int lane = threadIdx.x & 63;
    const float* A; const float* B; int r; int bi;
    if (row < PP) { A = imn; B = pcn; r = row; bi = bestI[r]; }
    else          { A = pcn; B = imn; r = row - PP; bi = bestPI[r]; }
    float2 av = *(const float2*)&A[(size_t)r * CC + lane * 2];
    float2 bv = *(const float2*)&B[(size_t)bi * CC + lane * 2];
    double s = (double)av.x * (double)bv.x + (double)av.y * (double)bv.y;
#pragma unroll
    for (int o = 32; o; o >>= 1) s += __shfl_xor(s, o);
    if (lane == 0) { if (row < PP) bestSd[r] = s; else bestPSd[r] = s; }
}

// ---------------- K3d: exact fp64 repair of ambiguous rows -----------------------
__global__ void k_recheck(const float* __restrict__ imn, const float* __restrict__ pcn,
                          const int* __restrict__ list, const int* __restrict__ cnt,
                          double* __restrict__ bestSd, int* __restrict__ bestI,
                          double* __restrict__ bestPSd, int* __restrict__ bestPI) {
    __shared__ double ad[CC];
    __shared__ double rv[4];
    __shared__ int    ri[4];
    int t = threadIdx.x;
    int wid = t >> 6, lane = t & 63;
    int total = *cnt;
    for (int e = blockIdx.x; e < total; e += gridDim.x) {
        __syncthreads();
        int ent = list[e];
        int r = ent & 0xffff, side = ent >> 16;
        const float* Arow = (side == 0 ? imn : pcn) + (size_t)r * CC;
        const float* B    = (side == 0 ? pcn : imn);
        if (t < CC) ad[t] = (double)Arow[t];
        __syncthreads();
        double bv = -1e300; int bi = 0x7fffffff;
        for (int j = t; j < NN; j += 256) {
            double s = 0.0;
#pragma unroll 8
            for (int c4 = 0; c4 < CC / 4; ++c4) {
                float4 b = *(const float4*)&B[(size_t)j * CC + c4 * 4];
                s += ad[c4 * 4 + 0] * (double)b.x;
                s += ad[c4 * 4 + 1] * (double)b.y;
                s += ad[c4 * 4 + 2] * (double)b.z;
                s += ad[c4 * 4 + 3] * (double)b.w;
            }
            if (s > bv || (s == bv && j < bi)) { bv = s; bi = j; }
        }
#pragma unroll
        for (int o = 32; o; o >>= 1) {
            double ov = __shfl_xor(bv, o); int oi = __shfl_xor(bi, o);
            if (ov > bv || (ov == bv && oi < bi)) { bv = ov; bi = oi; }
        }
        if (lane == 0) { rv[wid] = bv; ri[wid] = bi; }
        __syncthreads();
        if (t == 0) {
            for (int wv = 1; wv < 4; ++wv)
                if (rv[wv] > bv || (rv[wv] == bv && ri[wv] < bi)) { bv = rv[wv]; bi = ri[wv]; }
            if (side == 0) { bestSd[r] = bv; bestI[r] = bi; }
            else           { bestPSd[r] = bv; bestPI[r] = bi; }
        }
    }
}

// ---------------- K4: image sim/softmax + select output + seeding ----------------
__global__ void k_im_select(const float* __restrict__ imn,
                            const double* __restrict__ bestSd,
                            const int* __restrict__ bestI,
                            float* __restrict__ outSelect,
                            int* __restrict__ seed) {
    int p = blockIdx.x * 4 + (threadIdx.x >> 6);
    int lane = threadIdx.x & 63;
    int h = p >> 7;
    int w = p & 127;
    float2 ctr = *(const float2*)&imn[p * CC + lane * 2];

    double sim[KK];
#pragma unroll
    for (int k = 0; k < KK; ++k) {
        int di = k / 5 - 2, dj = k % 5 - 2;
        int hc = min(max(h + di, 0), HH - 1);
        int wc = min(max(w + dj, 0), WW - 1);
        int q = hc * WW + wc;
        float2 nv = *(const float2*)&imn[q * CC + lane * 2];
        double part = (double)ctr.x * (double)nv.x + (double)ctr.y * (double)nv.y;
#pragma unroll
        for (int o = 32; o; o >>= 1) part += __shfl_xor(part, o);
        sim[k] = part;
    }
    double mx = sim[0];
#pragma unroll
    for (int k = 1; k < KK; ++k) mx = fmax(mx, sim[k]);
    double sum = 0.0;
#pragma unroll
    for (int k = 0; k < KK; ++k) { sim[k] = exp(sim[k] - mx); sum += sim[k]; }
    double inv = 1.0 / sum;

    double sel[KK];
#pragma unroll
    for (int k = 0; k < KK; ++k) {
        int di = k / 5 - 2, dj = k % 5 - 2;
        int h2 = h + di, w2 = w + dj;
        bool valid = (h2 >= 0 && h2 < HH && w2 >= 0 && w2 < WW);
        int hc = min(max(h2, 0), HH - 1), wc = min(max(w2, 0), WW - 1);
        double conf = bestSd[hc * WW + wc];
        double so = valid ? (sim[k] * inv * conf) : (double)NEGV;
        if (lane == k) outSelect[k * PP + p] = (float)so;
        sel[k] = (k == 12) ? (double)NEGV : so;
    }

    int tk1 = 0, tk2 = 0, tk3 = 0, tk4 = 0;
    {
        unsigned chosen = 1u << 12;
#pragma unroll
        for (int s = 0; s < 4; ++s) {
            double bvv = -1e300; int bk = 0;
#pragma unroll
            for (int k = 0; k < KK; ++k)
                if (!((chosen >> k) & 1) && sel[k] > bvv) { bvv = sel[k]; bk = k; }
            chosen |= 1u << bk;
            if (s == 0) tk1 = bk; else if (s == 1) tk2 = bk; else if (s == 2) tk3 = bk; else tk4 = bk;
        }
    }
    if (lane == 0) {
        int tks[5] = {12, tk1, tk2, tk3, tk4};
#pragma unroll
        for (int s = 0; s < 5; ++s) {
            int k = tks[s];
            int di = k / 5 - 2, dj = k % 5 - 2;
            int h2 = h + di, w2 = w + dj;
            int pix = (h2 >= 0 && h2 < HH && w2 >= 0 && w2 < WW) ? (h2 * WW + w2) : -1;
            pix = min(max(pix, 0), PP - 1);
            seed[p * SPOT + s] = bestI[pix];
        }
    }
}

// ---------------- K6: pc sim/softmax + seeding -----------------------------------
__global__ void k_pc_select(const float* __restrict__ pcn,
                            const int* __restrict__ nb,
                            const double* __restrict__ bestPSd,
                            const int* __restrict__ bestPI,
                            int* __restrict__ pcseed) {
    int i = blockIdx.x * 4 + (threadIdx.x >> 6);
    int lane = threadIdx.x & 63;
    float2 ctr = *(const float2*)&pcn[i * CC + lane * 2];

    int nbr[KK];
#pragma unroll
    for (int k = 0; k < KK; ++k) nbr[k] = nb[i * KK + k];

    double sim[KK];
#pragma unroll
    for (int k = 0; k < KK; ++k) {
        float2 nv = *(const float2*)&pcn[nbr[k] * CC + lane * 2];
        double part = (double)ctr.x * (double)nv.x + (double)ctr.y * (double)nv.y;
#pragma unroll
        for (int o = 32; o; o >>= 1) part += __shfl_xor(part, o);
        sim[k] = part;
    }
    double mx = sim[0];
#pragma unroll
    for (int k = 1; k < KK; ++k) mx = fmax(mx, sim[k]);
    double sum = 0.0;
#pragma unroll
    for (int k = 0; k < KK; ++k) { sim[k] = exp(sim[k] - mx); sum += sim[k]; }
    double inv = 1.0 / sum;

    double sel[KK];
    sel[0] = (double)NEGV;
#pragma unroll
    for (int k = 1; k < KK; ++k) sel[k] = sim[k] * inv * bestPSd[nbr[k]];

    int tk1 = 0, tk2 = 0, tk3 = 0, tk4 = 0;
    {
        unsigned chosen = 0u;
#pragma unroll
        for (int s = 0; s < 4; ++s) {
            double bvv = -1e300; int bk = 0;
#pragma unroll
            for (int k = 0; k < KK; ++k)
                if (!((chosen >> k) & 1) && sel[k] > bvv) { bvv = sel[k]; bk = k; }
            chosen |= 1u << bk;
            if (s == 0) tk1 = bk; else if (s == 1) tk2 = bk; else if (s == 2) tk3 = bk; else tk4 = bk;
        }
    }
    if (lane == 0) {
        int tks[5] = {0, tk1, tk2, tk3, tk4};
#pragma unroll
        for (int s = 0; s < 5; ++s)
            pcseed[i * SPOT + s] = bestPI[nbr[tks[s]]];
    }
}

// ---------------- bitmap -> stable top-125 compaction ----------------------------
__device__ __forceinline__ void compact_bits(const unsigned* bits, int row,
                                             float* __restrict__ maskOut,
                                             float* __restrict__ idxOut, int lane) {
    int base = 0;
    for (int w = 0; w < 160 && base < 125; ++w) {
        unsigned word = bits[w];
        int cnt = __popc(word);
        if (lane < cnt) {
            unsigned v = word;
            for (int t = 0; t < lane; ++t) v &= v - 1;
            int pos = __ffs((int)v) - 1;
            idxOut[row * 125 + base + lane]  = (float)(w * 32 + pos);
            maskOut[row * 125 + base + lane] = 1.0f;
        }
        base += cnt;
    }
    for (int w = 0; w < 160 && base < 125; ++w) {
        unsigned word = ~bits[w];
        int cnt = __popc(word);
        int take = min(cnt, 125 - base);
        if (lane < take) {
            unsigned v = word;
            for (int t = 0; t < lane; ++t) v &= v - 1;
            int pos = __ffs((int)v) - 1;
            idxOut[row * 125 + base + lane]  = (float)(w * 32 + pos);
            maskOut[row * 125 + base + lane] = 0.0f;
        }
        base += take;
    }
}

// ---------------- K5: im spoting ------------------------------------------------
__global__ void k_im_spot(const int* __restrict__ seed, const int* __restrict__ nb,
                          float* __restrict__ maskOut, float* __restrict__ idxOut) {
    __shared__ unsigned bits[4][160];
    int wid = threadIdx.x >> 6, lane = threadIdx.x & 63;
    int p = blockIdx.x * 4 + wid;
    for (int w = lane; w < 160; w += 64) bits[wid][w] = 0u;
    __syncthreads();
    for (int e = lane; e < 125; e += 64) {
        int sd = seed[p * SPOT + e / 25];
        int pt = nb[sd * KK + (e % 25)];
        atomicOr(&bits[wid][pt >> 5], 1u << (pt & 31));
    }
    __syncthreads();
    compact_bits(bits[wid], p, maskOut, idxOut, lane);
}

// ---------------- K7: pc spoting ------------------------------------------------
__global__ void k_pc_spot(const int* __restrict__ pcseed,
                          float* __restrict__ maskOut, float* __restrict__ idxOut) {
    __shared__ unsigned bits[4][160];
    int wid = threadIdx.x >> 6, lane = threadIdx.x & 63;
    int i = blockIdx.x * 4 + wid;
    for (int w = lane; w < 160; w += 64) bits[wid][w] = 0u;
    __syncthreads();
    for (int e = lane; e < 125; e += 64) {
        int q = pcseed[i * SPOT + e / 25];
        int kk = e % 25;
        int r0 = q >> 7, c0 = q & 127;
        int r = min(max(r0 + kk / 5 - 2, 0), HH - 1);
        int c = min(max(c0 + kk % 5 - 2, 0), WW - 1);
        int pix = r * WW + c;
        atomicOr(&bits[wid][pix >> 5], 1u << (pix & 31));
    }
    __syncthreads();
    compact_bits(bits[wid], i, maskOut, idxOut, lane);
}

// ---------------- host ----------------------------------------------------------
extern "C" void kernel_launch(void* const* d_in, const int* in_sizes, int n_in,
                              void* d_out, int out_size, void* d_ws, size_t ws_size,
                              hipStream_t stream) {
    const float* imf = (const float*)d_in[0];
    const float* pcf = (const float*)d_in[1];
    const float* pts = (const float*)d_in[2];
    float* out = (float*)d_out;

    char* w = (char*)d_ws;
    double* bestSd  = (double*)w;  w += (size_t)PP * 8;
    double* bestPSd = (double*)w;  w += (size_t)NN * 8;
    float*  imn     = (float*)w;   w += (size_t)PP * CC * 4;
    float*  pcn     = (float*)w;   w += (size_t)NN * CC * 4;
    __half* imh     = (__half*)w;  w += (size_t)PP * CC * 2;
    __half* pch     = (__half*)w;  w += (size_t)NN * CC * 2;
    float*  pval    = (float*)w;   w += (size_t)2 * CSPL * PP * 4;
    float*  pv2     = (float*)w;   w += (size_t)2 * CSPL * PP * 4;
    int*    pidx    = (int*)w;     w += (size_t)2 * CSPL * PP * 4;
    int*    nb      = (int*)w;     w += (size_t)NN * KK * 4;
    int*    bestI   = (int*)w;     w += (size_t)PP * 4;
    int*    bestPI  = (int*)w;     w += (size_t)NN * 4;
    int*    seed    = (int*)w;     w += (size_t)PP * SPOT * 4;
    int*    pcseed  = (int*)w;     w += (size_t)NN * SPOT * 4;
    int*    list    = (int*)w;     w += (size_t)(PP + NN) * 4;
    int*    cnt     = (int*)w;     w += 256;

    float* outSelect = out;                       // (25, 5120)
    float* outMask   = out + KK * PP;             // (5120, 125)
    float* outIdx    = outMask + PP * 125;        // (5120, 125)
    float* outIdxPc  = outIdx + PP * 125;         // (5120, 125)
    float* outMaskPc = outIdxPc + NN * 125;       // (5120, 125)

    hipMemsetAsync(cnt, 0, 4, stream);
    k_normalize<<<(PP + NN) / 4, 256, 0, stream>>>(imf, pcf, imn, pcn, imh, pch);
    k_knn<<<NN, 256, 0, stream>>>(pts, nb);
    k_rowmax<<<dim3(PP / 128, CSPL, 2), 256, 0, stream>>>(imh, pch, pval, pv2, pidx);
    k_reduce_best<<<dim3(PP / 256, 2), 256, 0, stream>>>(pval, pv2, pidx,
                                                         bestI, bestPI, list, cnt);
    k_exact_best<<<2 * PP / 4, 256, 0, stream>>>(imn, pcn, bestI, bestPI, bestSd, bestPSd);
    k_recheck<<<1024, 256, 0, stream>>>(imn, pcn, list, cnt, bestSd, bestI, bestPSd, bestPI);
    k_im_select<<<PP / 4, 256, 0, stream>>>(imn, bestSd, bestI, outSelect, seed);
    k_pc_select<<<NN / 4, 256, 0, stream>>>(pcn, nb, bestPSd, bestPI, pcseed);
    k_im_spot<<<PP / 4, 256, 0, stream>>>(seed, nb, outMask, outIdx);
    k_pc_spot<<<NN / 4, 256, 0, stream>>>(pcseed, outMaskPc, outIdxPc);
}

// Round 6
// 543.274 us; speedup vs baseline: 1.1742x; 1.1742x over previous
//
#include <hip/hip_runtime.h>
#include <hip/hip_fp16.h>
#include <float.h>
#include <math.h>

#define HH 40
#define WW 128
#define PP 5120
#define NN 5120
#define CC 128
#define KK 25
#define SPOT 5
#define NEGV -1e8f

#define CSPL 8          // column segments for the MFMA screen (x2 wcol halves = 16 partials)
#define NSEG 16
#define EPSG 3e-3f      // fp16 screen gap threshold; sound bound 1.98e-3, 1.5x margin
#define EPS2 1e-4f      // fp32 recheck gap threshold; sound bound 7.6e-6, 13x margin
#define GMAX 160        // max row-groups (64 rows each) for batched fp32 recheck

typedef _Float16 half8 __attribute__((ext_vector_type(8)));
typedef float f32x4 __attribute__((ext_vector_type(4)));

// ---------------- K1: L2-normalize rows (fp64 norm; fp32 + fp16 copies) ----------
__global__ void k_normalize(const float* __restrict__ imf, const float* __restrict__ pcf,
                            float* __restrict__ imn, float* __restrict__ pcn,
                            __half* __restrict__ imh, __half* __restrict__ pch) {
    int row = blockIdx.x * 4 + (threadIdx.x >> 6);
    int lane = threadIdx.x & 63;
    const float* src; float* dst; __half* dsth; int r;
    if (row < PP) { src = imf; dst = imn; dsth = imh; r = row; }
    else          { src = pcf; dst = pcn; dsth = pch; r = row - PP; }
    float2 v = *(const float2*)&src[r * CC + lane * 2];
    double ss = (double)v.x * (double)v.x + (double)v.y * (double)v.y;
#pragma unroll
    for (int o = 32; o; o >>= 1) ss += __shfl_xor(ss, o);
    double inv = 1.0 / fmax(sqrt(ss), 1e-12);
    float2 o2 = make_float2((float)((double)v.x * inv), (float)((double)v.y * inv));
    *(float2*)&dst[r * CC + lane * 2] = o2;
    *(__half2*)&dsth[r * CC + lane * 2] = __floats2half2_rn(o2.x, o2.y);
}

// ---------------- K2: KNN top-25, register-tournament ----------------------------
__global__ __launch_bounds__(256) void k_knn(const float* __restrict__ pts,
                                             int* __restrict__ nb) {
    __shared__ double sv[2][4];
    __shared__ int    si[2][4];
    int i = blockIdx.x;
    int t = threadIdx.x;
    int wid = t >> 6, lane = t & 63;
    double px = pts[i * 3 + 0], py = pts[i * 3 + 1], pz = pts[i * 3 + 2];

    double d[20];
    int base = t * 20;
    double lv = DBL_MAX; int li = 0x7fffffff;
#pragma unroll
    for (int e = 0; e < 20; ++e) {
        int j = base + e;
        double dx = px - (double)pts[j * 3 + 0];
        double dy = py - (double)pts[j * 3 + 1];
        double dz = pz - (double)pts[j * 3 + 2];
        double v = dx * dx + dy * dy + dz * dz;
        d[e] = v;
        if (v < lv) { lv = v; li = j; }
    }

    unsigned removed = 0u;
    for (int it = 0; it < KK; ++it) {
        double bv = lv; int bi = li;
#pragma unroll
        for (int o = 32; o; o >>= 1) {
            double ov = __shfl_xor(bv, o); int oi = __shfl_xor(bi, o);
            if (ov < bv || (ov == bv && oi < bi)) { bv = ov; bi = oi; }
        }
        int par = it & 1;
        if (lane == 0) { sv[par][wid] = bv; si[par][wid] = bi; }
        __syncthreads();
        bv = sv[par][0]; bi = si[par][0];
#pragma unroll
        for (int wv = 1; wv < 4; ++wv) {
            double ov = sv[par][wv]; int oi = si[par][wv];
            if (ov < bv || (ov == bv && oi < bi)) { bv = ov; bi = oi; }
        }
        if (t == 0) nb[i * KK + it] = bi;
        if (bi >= base && bi < base + 20) {
            removed |= 1u << (bi - base);
            lv = DBL_MAX; li = 0x7fffffff;
#pragma unroll
            for (int e = 0; e < 20; ++e) {
                bool alive = !((removed >> e) & 1u);
                if (alive && d[e] < lv) { lv = d[e]; li = base + e; }
            }
        }
    }
}

// ---------------- K3: fp16 MFMA cosine screen: per-row (best, 2nd, argmax) -------
// blockIdx.z: 0 rows=im cols=pc, 1 rows=pc cols=im. Block 128 rows x 640-col seg,
// 4 waves (2 wrow x 2 wcol); partials indexed by (z, y*2 + wcol) -- RACE FIX: the
// two column-half waves write DISTINCT partial slots now.
__global__ __launch_bounds__(256, 2) void k_rowmax(const __half* __restrict__ imh,
                                                   const __half* __restrict__ pch,
                                                   float* __restrict__ pval,
                                                   float* __restrict__ pv2,
                                                   int* __restrict__ pidx) {
    const __half* Ah = (blockIdx.z == 0) ? imh : pch;
    const __half* Bh = (blockIdx.z == 0) ? pch : imh;
    __shared__ char As[128 * 256];
    __shared__ char Bs[128 * 256];

    int t = threadIdx.x;
    int wave = t >> 6, l = t & 63;
    int wrow = wave >> 1, wcol = wave & 1;
    int lg = l >> 4, lc = l & 15;
    int rb = blockIdx.x * 128;
    int segbase = blockIdx.y * (NN / CSPL);

#pragma unroll
    for (int i = 0; i < 8; ++i) {
        int u = t + i * 256;
        int row = u >> 4, kb = u & 15;
        uint4 v = *(const uint4*)&Ah[(size_t)(rb + row) * CC + kb * 8];
        *(uint4*)(As + row * 256 + ((kb * 16) ^ ((row & 7) << 4))) = v;
    }

    float v1[4][4], v2[4][4]; int i1[4][4];
#pragma unroll
    for (int rt = 0; rt < 4; ++rt)
#pragma unroll
        for (int rg = 0; rg < 4; ++rg) { v1[rt][rg] = -1e30f; v2[rt][rg] = -1e30f; i1[rt][rg] = 0; }

    for (int ch = 0; ch < NN / CSPL; ch += 128) {
#pragma unroll
        for (int i = 0; i < 8; ++i) {
            int u = t + i * 256;
            int row = u >> 4, kb = u & 15;
            uint4 v = *(const uint4*)&Bh[(size_t)(segbase + ch + row) * CC + kb * 8];
            *(uint4*)(Bs + row * 256 + ((kb * 16) ^ ((row & 7) << 4))) = v;
        }
        __syncthreads();

        f32x4 acc[4][4];
#pragma unroll
        for (int rt = 0; rt < 4; ++rt)
#pragma unroll
            for (int ct = 0; ct < 4; ++ct) acc[rt][ct] = (f32x4){0.f, 0.f, 0.f, 0.f};

#pragma unroll
        for (int ks = 0; ks < 4; ++ks) {
            int kb = ks * 64 + lg * 16;
            half8 a[4], b[4];
#pragma unroll
            for (int rt = 0; rt < 4; ++rt) {
                int row = wrow * 64 + rt * 16 + lc;
                a[rt] = *(const half8*)(As + row * 256 + (kb ^ ((row & 7) << 4)));
            }
#pragma unroll
            for (int ct = 0; ct < 4; ++ct) {
                int row = wcol * 64 + ct * 16 + lc;
                b[ct] = *(const half8*)(Bs + row * 256 + (kb ^ ((row & 7) << 4)));
            }
#pragma unroll
            for (int rt = 0; rt < 4; ++rt)
#pragma unroll
                for (int ct = 0; ct < 4; ++ct)
                    acc[rt][ct] = __builtin_amdgcn_mfma_f32_16x16x32_f16(
                        a[rt], b[ct], acc[rt][ct], 0, 0, 0);
        }

        int colb = segbase + ch + wcol * 64 + lc;
#pragma unroll
        for (int rt = 0; rt < 4; ++rt)
#pragma unroll
            for (int ct = 0; ct < 4; ++ct) {
                int c = colb + ct * 16;
#pragma unroll
                for (int rg = 0; rg < 4; ++rg) {
                    float v = acc[rt][ct][rg];
                    bool gt = v > v1[rt][rg];
                    v2[rt][rg] = gt ? v1[rt][rg] : fmaxf(v2[rt][rg], v);  // tie -> gap 0 -> recheck
                    i1[rt][rg] = gt ? c : i1[rt][rg];
                    v1[rt][rg] = gt ? v : v1[rt][rg];
                }
            }
        __syncthreads();
    }

#pragma unroll
    for (int rt = 0; rt < 4; ++rt)
#pragma unroll
        for (int rg = 0; rg < 4; ++rg) {
            float a1 = v1[rt][rg], a2 = v2[rt][rg]; int ai = i1[rt][rg];
#pragma unroll
            for (int o = 1; o < 16; o <<= 1) {
                float o1 = __shfl_xor(a1, o);
                float o2v = __shfl_xor(a2, o);
                int   oi = __shfl_xor(ai, o);
                if (o1 > a1) { a2 = fmaxf(a1, o2v); a1 = o1; ai = oi; }
                else         { a2 = fmaxf(a2, o1); }
            }
            if (lc == 0) {
                int seg = blockIdx.y * 2 + wcol;
                size_t o = ((size_t)blockIdx.z * NSEG + seg) * PP
                         + rb + wrow * 64 + rt * 16 + lg * 4 + rg;
                pval[o] = a1; pv2[o] = a2; pidx[o] = ai;
            }
        }
}

// ---------------- K3b: reduce 16 partials/side, flag ambiguous rows --------------
__global__ void k_reduce_best(const float* __restrict__ pval, const float* __restrict__ pv2,
                              const int* __restrict__ pidx,
                              int* __restrict__ bestI, int* __restrict__ bestPI,
                              int* __restrict__ listA, int* __restrict__ listB,
                              int* __restrict__ cnt) {
    int r = blockIdx.x * 256 + threadIdx.x;
    int side = blockIdx.y;
    size_t base = (size_t)side * NSEG * PP + r;
    float v1 = pval[base], v2 = pv2[base]; int i1 = pidx[base];
    for (int s = 1; s < NSEG; ++s) {
        float ov1 = pval[base + (size_t)s * PP];
        float ov2 = pv2[base + (size_t)s * PP];
        int   oi  = pidx[base + (size_t)s * PP];
        if (ov1 > v1) { v2 = fmaxf(v1, ov2); v1 = ov1; i1 = oi; }
        else          { v2 = fmaxf(v2, ov1); }
    }
    if (side == 0) bestI[r] = i1; else bestPI[r] = i1;
    if (v1 - v2 < EPSG) {
        int slot = atomicAdd(&cnt[side], 1);
        (side ? listB : listA)[slot] = r;
    }
}

// ---------------- K3c: batched fp32 recheck of flagged rows (64-row tiles) -------
// grid (GMAX, 8, 2). Each block: 64 gathered A-rows x one 640-col segment, fp32
// 4x4 register tiles, per-row (best, 2nd, argmax) partials.
__global__ __launch_bounds__(256, 2) void k_recheck32(const float* __restrict__ imn,
                                                      const float* __restrict__ pcn,
                                                      const int* __restrict__ listA,
                                                      const int* __restrict__ listB,
                                                      const int* __restrict__ cnt,
                                                      float* __restrict__ q1,
                                                      float* __restrict__ q2,
                                                      int* __restrict__ qi) {
    int side = blockIdx.z, g = blockIdx.x, seg = blockIdx.y;
    int n = cnt[side];
    if (g * 64 >= n) return;
    const float* A = side ? pcn : imn;
    const float* B = side ? imn : pcn;
    const int* lst = side ? listB : listA;

    __shared__ float As[64 * CC];
    __shared__ float Bs[64 * CC];
    int t = threadIdx.x;

    for (int q = t; q < 64 * 32; q += 256) {
        int slot = q >> 5, c4 = q & 31;
        int e = g * 64 + slot;
        int r = (e < n) ? lst[e] : lst[0];
        float4 v = *(const float4*)&A[(size_t)r * CC + c4 * 4];
        int sw = ((slot >> 2) & 7) << 2;
        *(float4*)&As[slot * CC + ((c4 * 4) ^ sw)] = v;
    }

    int ty = t >> 4, tx = t & 15;
    int swA = (ty & 7) << 2;
    int swB = (tx & 7) << 2;

    float bv[4], bv2[4]; int bi[4];
#pragma unroll
    for (int ii = 0; ii < 4; ++ii) { bv[ii] = -1e30f; bv2[ii] = -1e30f; bi[ii] = 0; }

    int segBase = seg * (NN / 8);
    for (int ch = 0; ch < NN / 8; ch += 64) {
        __syncthreads();
        for (int q = t; q < 64 * 32; q += 256) {
            int row = q >> 5, c4 = q & 31;
            float4 v = *(const float4*)&B[(size_t)(segBase + ch + row) * CC + c4 * 4];
            int sw = ((row >> 2) & 7) << 2;
            *(float4*)&Bs[row * CC + ((c4 * 4) ^ sw)] = v;
        }
        __syncthreads();

        float acc[4][4];
#pragma unroll
        for (int ii = 0; ii < 4; ++ii)
#pragma unroll
            for (int jj = 0; jj < 4; ++jj) acc[ii][jj] = 0.0f;

#pragma unroll 4
        for (int cs = 0; cs < CC / 4; ++cs) {
            int c = cs << 2;
            float4 af[4], bf[4];
#pragma unroll
            for (int ii = 0; ii < 4; ++ii)
                af[ii] = *(const float4*)&As[(ty * 4 + ii) * CC + (c ^ swA)];
#pragma unroll
            for (int jj = 0; jj < 4; ++jj)
                bf[jj] = *(const float4*)&Bs[(tx * 4 + jj) * CC + (c ^ swB)];
#pragma unroll
            for (int ii = 0; ii < 4; ++ii)
#pragma unroll
                for (int jj = 0; jj < 4; ++jj) {
                    acc[ii][jj] += af[ii].x * bf[jj].x;
                    acc[ii][jj] += af[ii].y * bf[jj].y;
                    acc[ii][jj] += af[ii].z * bf[jj].z;
                    acc[ii][jj] += af[ii].w * bf[jj].w;
                }
        }

        int cb = segBase + ch + tx * 4;
#pragma unroll
        for (int ii = 0; ii < 4; ++ii)
#pragma unroll
            for (int jj = 0; jj < 4; ++jj) {
                float v = acc[ii][jj];
                if (v > bv[ii]) { bv2[ii] = bv[ii]; bv[ii] = v; bi[ii] = cb + jj; }
                else            { bv2[ii] = fmaxf(bv2[ii], v); }
            }
    }

#pragma unroll
    for (int ii = 0; ii < 4; ++ii) {
        float a1 = bv[ii], a2 = bv2[ii]; int ai = bi[ii];
#pragma unroll
        for (int o = 1; o < 16; o <<= 1) {
            float o1 = __shfl_xor(a1, o);
            float o2v = __shfl_xor(a2, o);
            int   oi = __shfl_xor(ai, o);
            if (o1 > a1) { a2 = fmaxf(a1, o2v); a1 = o1; ai = oi; }
            else         { a2 = fmaxf(a2, o1); }
        }
        if (tx == 0) {
            size_t o = ((size_t)(side * GMAX + g) * 8 + seg) * 64 + ty * 4 + ii;
            q1[o] = a1; q2[o] = a2; qi[o] = ai;
        }
    }
}

// ---------------- K3d: reduce fp32 recheck partials; funnel near-ties ------------
__global__ void k_reduce2(const float* __restrict__ q1, const float* __restrict__ q2,
                          const int* __restrict__ qi,
                          const int* __restrict__ listA, const int* __restrict__ listB,
                          int* __restrict__ cnt,
                          int* __restrict__ bestI, int* __restrict__ bestPI,
                          int* __restrict__ list2) {
    int side = blockIdx.y;
    int e = blockIdx.x * 64 + threadIdx.x;
    if (e >= cnt[side]) return;
    int g = e >> 6, slot = e & 63;
    size_t base = (size_t)(side * GMAX + g) * 8 * 64 + slot;
    float v1 = q1[base], v2 = q2[base]; int i1 = qi[base];
#pragma unroll
    for (int s = 1; s < 8; ++s) {
        float ov1 = q1[base + s * 64];
        float ov2 = q2[base + s * 64];
        int   oi  = qi[base + s * 64];
        if (ov1 > v1) { v2 = fmaxf(v1, ov2); v1 = ov1; i1 = oi; }
        else          { v2 = fmaxf(v2, ov1); }
    }
    int r = (side ? listB : listA)[e];
    if (v1 - v2 < EPS2) {
        int s2 = atomicAdd(&cnt[2], 1);
        list2[s2] = r | (side << 16);
    } else {
        if (side == 0) bestI[r] = i1; else bestPI[r] = i1;
    }
}

// ---------------- K3e: exact fp64 best VALUE for every row -----------------------
__global__ void k_exact_best(const float* __restrict__ imn, const float* __restrict__ pcn,
                             const int* __restrict__ bestI, const int* __restrict__ bestPI,
                             double* __restrict__ bestSd, double* __restrict__ bestPSd) {
    int row = blockIdx.x * 4 + (threadIdx.x >> 6);
    int lane = threadIdx.x & 63;
    const float* A; const float* B; int r; int bi;
    if (row < PP) { A = imn; B = pcn; r = row; bi = bestI[r]; }
    else          { A = pcn; B = imn; r = row - PP; bi = bestPI[r]; }
    float2 av = *(const float2*)&A[(size_t)r * CC + lane * 2];
    float2 bv = *(const float2*)&B[(size_t)bi * CC + lane * 2];
    double s = (double)av.x * (double)bv.x + (double)av.y * (double)bv.y;
#pragma unroll
    for (int o = 32; o; o >>= 1) s += __shfl_xor(s, o);
    if (lane == 0) { if (row < PP) bestSd[r] = s; else bestPSd[r] = s; }
}

// ---------------- K3f: exact fp64 repair of remaining near-ties ------------------
__global__ void k_recheck64(const float* __restrict__ imn, const float* __restrict__ pcn,
                            const int* __restrict__ list2, const int* __restrict__ cnt,
                            double* __restrict__ bestSd, int* __restrict__ bestI,
                            double* __restrict__ bestPSd, int* __restrict__ bestPI) {
    __shared__ double ad[CC];
    __shared__ double rv[4];
    __shared__ int    ri[4];
    int t = threadIdx.x;
    int wid = t >> 6, lane = t & 63;
    int total = cnt[2];
    for (int e = blockIdx.x; e < total; e += gridDim.x) {
        __syncthreads();
        int ent = list2[e];
        int r = ent & 0xffff, side = ent >> 16;
        const float* Arow = (side == 0 ? imn : pcn) + (size_t)r * CC;
        const float* B    = (side == 0 ? pcn : imn);
        if (t < CC) ad[t] = (double)Arow[t];
        __syncthreads();
        double bv = -1e300; int bi = 0x7fffffff;
        for (int j = t; j < NN; j += 256) {
            double s0 = 0.0, s1 = 0.0, s2 = 0.0, s3 = 0.0;
#pragma unroll 8
            for (int c4 = 0; c4 < CC / 4; ++c4) {
                float4 b = *(const float4*)&B[(size_t)j * CC + c4 * 4];
                s0 += ad[c4 * 4 + 0] * (double)b.x;
                s1 += ad[c4 * 4 + 1] * (double)b.y;
                s2 += ad[c4 * 4 + 2] * (double)b.z;
                s3 += ad[c4 * 4 + 3] * (double)b.w;
            }
            double s = (s0 + s1) + (s2 + s3);
            if (s > bv || (s == bv && j < bi)) { bv = s; bi = j; }
        }
#pragma unroll
        for (int o = 32; o; o >>= 1) {
            double ov = __shfl_xor(bv, o); int oi = __shfl_xor(bi, o);
            if (ov > bv || (ov == bv && oi < bi)) { bv = ov; bi = oi; }
        }
        if (lane == 0) { rv[wid] = bv; ri[wid] = bi; }
        __syncthreads();
        if (t == 0) {
            for (int wv = 1; wv < 4; ++wv)
                if (rv[wv] > bv || (rv[wv] == bv && ri[wv] < bi)) { bv = rv[wv]; bi = ri[wv]; }
            if (side == 0) { bestSd[r] = bv; bestI[r] = bi; }
            else           { bestPSd[r] = bv; bestPI[r] = bi; }
        }
    }
}

// ---------------- K4: image sim/softmax + select output + seeding ----------------
__global__ void k_im_select(const float* __restrict__ imn,
                            const double* __restrict__ bestSd,
                            const int* __restrict__ bestI,
                            float* __restrict__ outSelect,
                            int* __restrict__ seed) {
    int p = blockIdx.x * 4 + (threadIdx.x >> 6);
    int lane = threadIdx.x & 63;
    int h = p >> 7;
    int w = p & 127;
    float2 ctr = *(const float2*)&imn[p * CC + lane * 2];

    double sim[KK];
#pragma unroll
    for (int k = 0; k < KK; ++k) {
        int di = k / 5 - 2, dj = k % 5 - 2;
        int hc = min(max(h + di, 0), HH - 1);
        int wc = min(max(w + dj, 0), WW - 1);
        int q = hc * WW + wc;
        float2 nv = *(const float2*)&imn[q * CC + lane * 2];
        double part = (double)ctr.x * (double)nv.x + (double)ctr.y * (double)nv.y;
#pragma unroll
        for (int o = 32; o; o >>= 1) part += __shfl_xor(part, o);
        sim[k] = part;
    }
    double mx = sim[0];
#pragma unroll
    for (int k = 1; k < KK; ++k) mx = fmax(mx, sim[k]);
    double sum = 0.0;
#pragma unroll
    for (int k = 0; k < KK; ++k) { sim[k] = exp(sim[k] - mx); sum += sim[k]; }
    double inv = 1.0 / sum;

    double sel[KK];
#pragma unroll
    for (int k = 0; k < KK; ++k) {
        int di = k / 5 - 2, dj = k % 5 - 2;
        int h2 = h + di, w2 = w + dj;
        bool valid = (h2 >= 0 && h2 < HH && w2 >= 0 && w2 < WW);
        int hc = min(max(h2, 0), HH - 1), wc = min(max(w2, 0), WW - 1);
        double conf = bestSd[hc * WW + wc];
        double so = valid ? (sim[k] * inv * conf) : (double)NEGV;
        if (lane == k) outSelect[k * PP + p] = (float)so;
        sel[k] = (k == 12) ? (double)NEGV : so;
    }

    int tk1 = 0, tk2 = 0, tk3 = 0, tk4 = 0;
    {
        unsigned chosen = 1u << 12;
#pragma unroll
        for (int s = 0; s < 4; ++s) {
            double bvv = -1e300; int bk = 0;
#pragma unroll
            for (int k = 0; k < KK; ++k)
                if (!((chosen >> k) & 1) && sel[k] > bvv) { bvv = sel[k]; bk = k; }
            chosen |= 1u << bk;
            if (s == 0) tk1 = bk; else if (s == 1) tk2 = bk; else if (s == 2) tk3 = bk; else tk4 = bk;
        }
    }
    if (lane == 0) {
        int tks[5] = {12, tk1, tk2, tk3, tk4};
#pragma unroll
        for (int s = 0; s < 5; ++s) {
            int k = tks[s];
            int di = k / 5 - 2, dj = k % 5 - 2;
            int h2 = h + di, w2 = w + dj;
            int pix = (h2 >= 0 && h2 < HH && w2 >= 0 && w2 < WW) ? (h2 * WW + w2) : -1;
            pix = min(max(pix, 0), PP - 1);
            seed[p * SPOT + s] = bestI[pix];
        }
    }
}

// ---------------- K6: pc sim/softmax + seeding -----------------------------------
__global__ void k_pc_select(const float* __restrict__ pcn,
                            const int* __restrict__ nb,
                            const double* __restrict__ bestPSd,
                            const int* __restrict__ bestPI,
                            int* __restrict__ pcseed) {
    int i = blockIdx.x * 4 + (threadIdx.x >> 6);
    int lane = threadIdx.x & 63;
    float2 ctr = *(const float2*)&pcn[i * CC + lane * 2];

    int nbr[KK];
#pragma unroll
    for (int k = 0; k < KK; ++k) nbr[k] = nb[i * KK + k];

    double sim[KK];
#pragma unroll
    for (int k = 0; k < KK; ++k) {
        float2 nv = *(const float2*)&pcn[nbr[k] * CC + lane * 2];
        double part = (double)ctr.x * (double)nv.x + (double)ctr.y * (double)nv.y;
#pragma unroll
        for (int o = 32; o; o >>= 1) part += __shfl_xor(part, o);
        sim[k] = part;
    }
    double mx = sim[0];
#pragma unroll
    for (int k = 1; k < KK; ++k) mx = fmax(mx, sim[k]);
    double sum = 0.0;
#pragma unroll
    for (int k = 0; k < KK; ++k) { sim[k] = exp(sim[k] - mx); sum += sim[k]; }
    double inv = 1.0 / sum;

    double sel[KK];
    sel[0] = (double)NEGV;
#pragma unroll
    for (int k = 1; k < KK; ++k) sel[k] = sim[k] * inv * bestPSd[nbr[k]];

    int tk1 = 0, tk2 = 0, tk3 = 0, tk4 = 0;
    {
        unsigned chosen = 0u;
#pragma unroll
        for (int s = 0; s < 4; ++s) {
            double bvv = -1e300; int bk = 0;
#pragma unroll
            for (int k = 0; k < KK; ++k)
                if (!((chosen >> k) & 1) && sel[k] > bvv) { bvv = sel[k]; bk = k; }
            chosen |= 1u << bk;
            if (s == 0) tk1 = bk; else if (s == 1) tk2 = bk; else if (s == 2) tk3 = bk; else tk4 = bk;
        }
    }
    if (lane == 0) {
        int tks[5] = {0, tk1, tk2, tk3, tk4};
#pragma unroll
        for (int s = 0; s < 5; ++s)
            pcseed[i * SPOT + s] = bestPI[nbr[tks[s]]];
    }
}

// ---------------- bitmap -> stable top-125 compaction ----------------------------
__device__ __forceinline__ void compact_bits(const unsigned* bits, int row,
                                             float* __restrict__ maskOut,
                                             float* __restrict__ idxOut, int lane) {
    int base = 0;
    for (int w = 0; w < 160 && base < 125; ++w) {
        unsigned word = bits[w];
        int cnt = __popc(word);
        if (lane < cnt) {
            unsigned v = word;
            for (int t = 0; t < lane; ++t) v &= v - 1;
            int pos = __ffs((int)v) - 1;
            idxOut[row * 125 + base + lane]  = (float)(w * 32 + pos);
            maskOut[row * 125 + base + lane] = 1.0f;
        }
        base += cnt;
    }
    for (int w = 0; w < 160 && base < 125; ++w) {
        unsigned word = ~bits[w];
        int cnt = __popc(word);
        int take = min(cnt, 125 - base);
        if (lane < take) {
            unsigned v = word;
            for (int t = 0; t < lane; ++t) v &= v - 1;
            int pos = __ffs((int)v) - 1;
            idxOut[row * 125 + base + lane]  = (float)(w * 32 + pos);
            maskOut[row * 125 + base + lane] = 0.0f;
        }
        base += take;
    }
}

// ---------------- K5: im spoting ------------------------------------------------
__global__ void k_im_spot(const int* __restrict__ seed, const int* __restrict__ nb,
                          float* __restrict__ maskOut, float* __restrict__ idxOut) {
    __shared__ unsigned bits[4][160];
    int wid = threadIdx.x >> 6, lane = threadIdx.x & 63;
    int p = blockIdx.x * 4 + wid;
    for (int w = lane; w < 160; w += 64) bits[wid][w] = 0u;
    __syncthreads();
    for (int e = lane; e < 125; e += 64) {
        int sd = seed[p * SPOT + e / 25];
        int pt = nb[sd * KK + (e % 25)];
        atomicOr(&bits[wid][pt >> 5], 1u << (pt & 31));
    }
    __syncthreads();
    compact_bits(bits[wid], p, maskOut, idxOut, lane);
}

// ---------------- K7: pc spoting ------------------------------------------------
__global__ void k_pc_spot(const int* __restrict__ pcseed,
                          float* __restrict__ maskOut, float* __restrict__ idxOut) {
    __shared__ unsigned bits[4][160];
    int wid = threadIdx.x >> 6, lane = threadIdx.x & 63;
    int i = blockIdx.x * 4 + wid;
    for (int w = lane; w < 160; w += 64) bits[wid][w] = 0u;
    __syncthreads();
    for (int e = lane; e < 125; e += 64) {
        int q = pcseed[i * SPOT + e / 25];
        int kk = e % 25;
        int r0 = q >> 7, c0 = q & 127;
        int r = min(max(r0 + kk / 5 - 2, 0), HH - 1);
        int c = min(max(c0 + kk % 5 - 2, 0), WW - 1);
        int pix = r * WW + c;
        atomicOr(&bits[wid][pix >> 5], 1u << (pix & 31));
    }
    __syncthreads();
    compact_bits(bits[wid], i, maskOut, idxOut, lane);
}

// ---------------- host ----------------------------------------------------------
extern "C" void kernel_launch(void* const* d_in, const int* in_sizes, int n_in,
                              void* d_out, int out_size, void* d_ws, size_t ws_size,
                              hipStream_t stream) {
    const float* imf = (const float*)d_in[0];
    const float* pcf = (const float*)d_in[1];
    const float* pts = (const float*)d_in[2];
    float* out = (float*)d_out;

    char* w = (char*)d_ws;
    double* bestSd  = (double*)w;  w += (size_t)PP * 8;
    double* bestPSd = (double*)w;  w += (size_t)NN * 8;
    float*  imn     = (float*)w;   w += (size_t)PP * CC * 4;
    float*  pcn     = (float*)w;   w += (size_t)NN * CC * 4;
    __half* imh     = (__half*)w;  w += (size_t)PP * CC * 2;
    __half* pch     = (__half*)w;  w += (size_t)NN * CC * 2;
    float*  pval    = (float*)w;   w += (size_t)2 * NSEG * PP * 4;
    float*  pv2     = (float*)w;   w += (size_t)2 * NSEG * PP * 4;
    int*    pidx    = (int*)w;     w += (size_t)2 * NSEG * PP * 4;
    float*  q1      = (float*)w;   w += (size_t)2 * GMAX * 8 * 64 * 4;
    float*  q2      = (float*)w;   w += (size_t)2 * GMAX * 8 * 64 * 4;
    int*    qi      = (int*)w;     w += (size_t)2 * GMAX * 8 * 64 * 4;
    int*    nb      = (int*)w;     w += (size_t)NN * KK * 4;
    int*    bestI   = (int*)w;     w += (size_t)PP * 4;
    int*    bestPI  = (int*)w;     w += (size_t)NN * 4;
    int*    seed    = (int*)w;     w += (size_t)PP * SPOT * 4;
    int*    pcseed  = (int*)w;     w += (size_t)NN * SPOT * 4;
    int*    listA   = (int*)w;     w += (size_t)PP * 4;
    int*    listB   = (int*)w;     w += (size_t)NN * 4;
    int*    list2   = (int*)w;     w += (size_t)(PP + NN) * 4;
    int*    cnt     = (int*)w;     w += 256;

    float* outSelect = out;                       // (25, 5120)
    float* outMask   = out + KK * PP;             // (5120, 125)
    float* outIdx    = outMask + PP * 125;        // (5120, 125)
    float* outIdxPc  = outIdx + PP * 125;         // (5120, 125)
    float* outMaskPc = outIdxPc + NN * 125;       // (5120, 125)

    hipMemsetAsync(cnt, 0, 16, stream);
    k_normalize<<<(PP + NN) / 4, 256, 0, stream>>>(imf, pcf, imn, pcn, imh, pch);
    k_knn<<<NN, 256, 0, stream>>>(pts, nb);
    k_rowmax<<<dim3(PP / 128, CSPL, 2), 256, 0, stream>>>(imh, pch, pval, pv2, pidx);
    k_reduce_best<<<dim3(PP / 256, 2), 256, 0, stream>>>(pval, pv2, pidx,
                                                         bestI, bestPI, listA, listB, cnt);
    k_recheck32<<<dim3(GMAX, 8, 2), 256, 0, stream>>>(imn, pcn, listA, listB, cnt,
                                                      q1, q2, qi);
    k_reduce2<<<dim3(GMAX, 2), 64, 0, stream>>>(q1, q2, qi, listA, listB, cnt,
                                                bestI, bestPI, list2);
    k_exact_best<<<2 * PP / 4, 256, 0, stream>>>(imn, pcn, bestI, bestPI, bestSd, bestPSd);
    k_recheck64<<<256, 256, 0, stream>>>(imn, pcn, list2, cnt,
                                         bestSd, bestI, bestPSd, bestPI);
    k_im_select<<<PP / 4, 256, 0, stream>>>(imn, bestSd, bestI, outSelect, seed);
    k_pc_select<<<NN / 4, 256, 0, stream>>>(pcn, nb, bestPSd, bestPI, pcseed);
    k_im_spot<<<PP / 4, 256, 0, stream>>>(seed, nb, outMask, outIdx);
    k_pc_spot<<<NN / 4, 256, 0, stream>>>(pcseed, outMaskPc, outIdxPc);
}

// Round 7
// 454.396 us; speedup vs baseline: 1.4038x; 1.1956x over previous
//
#include <hip/hip_runtime.h>
#include <hip/hip_fp16.h>
#include <float.h>
#include <math.h>

#define HH 40
#define WW 128
#define PP 5120
#define NN 5120
#define CC 128
#define KK 25
#define SPOT 5
#define NEGV -1e8f

#define CSPL 8          // column segments for the MFMA screen (x2 wcol halves = 16 partials)
#define NSEG 16
#define EPSG 3e-3f      // fp16 screen gap threshold; sound bound 1.98e-3, 1.5x margin
#define EPS2 1e-4f      // fp32 recheck gap threshold; sound bound 7.6e-6, 13x margin
#define GMAX 160        // max row-groups (64 rows each) for batched fp32 recheck

typedef _Float16 half8 __attribute__((ext_vector_type(8)));
typedef float f32x4 __attribute__((ext_vector_type(4)));

// ---------------- K1: L2-normalize rows (fp64 norm; fp32 + fp16 copies) ----------
__global__ void k_normalize(const float* __restrict__ imf, const float* __restrict__ pcf,
                            float* __restrict__ imn, float* __restrict__ pcn,
                            __half* __restrict__ imh, __half* __restrict__ pch) {
    int row = blockIdx.x * 4 + (threadIdx.x >> 6);
    int lane = threadIdx.x & 63;
    const float* src; float* dst; __half* dsth; int r;
    if (row < PP) { src = imf; dst = imn; dsth = imh; r = row; }
    else          { src = pcf; dst = pcn; dsth = pch; r = row - PP; }
    float2 v = *(const float2*)&src[r * CC + lane * 2];
    double ss = (double)v.x * (double)v.x + (double)v.y * (double)v.y;
#pragma unroll
    for (int o = 32; o; o >>= 1) ss += __shfl_xor(ss, o);
    double inv = 1.0 / fmax(sqrt(ss), 1e-12);
    float2 o2 = make_float2((float)((double)v.x * inv), (float)((double)v.y * inv));
    *(float2*)&dst[r * CC + lane * 2] = o2;
    *(__half2*)&dsth[r * CC + lane * 2] = __floats2half2_rn(o2.x, o2.y);
}

// ---------------- K2: KNN top-25 via 8-bit radix-select on fp32 keys -------------
// d2 computed with explicit rn ops = bitwise identical to the reference's fp32
// ((dx*dx+dy*dy)+dz*dz). d2>=0 so its bit pattern is a monotone uint32 key;
// (key, index) ascending == lax.top_k(-d2) order incl. tie-break. 4 radix levels
// find the exact threshold key K + tie count; key<K entries rank-sorted in
// parallel; remaining slots filled from key==K by ascending index.
__global__ __launch_bounds__(256) void k_knn(const float* __restrict__ pts,
                                             int* __restrict__ nb) {
    __shared__ int hist[256];
    __shared__ int wsum[4];
    __shared__ int wmin[4];
    __shared__ int s_b, s_need, s_cntLess;
    __shared__ unsigned long long sel[32];
    int i = blockIdx.x, t = threadIdx.x;
    int wid = t >> 6, lane = t & 63;
    float px = pts[i * 3 + 0], py = pts[i * 3 + 1], pz = pts[i * 3 + 2];

    unsigned k[20];
    int base = t * 20;
#pragma unroll
    for (int e = 0; e < 20; ++e) {
        int j = base + e;
        float dx = __fsub_rn(px, pts[j * 3 + 0]);
        float dy = __fsub_rn(py, pts[j * 3 + 1]);
        float dz = __fsub_rn(pz, pts[j * 3 + 2]);
        float s = __fadd_rn(__fadd_rn(__fmul_rn(dx, dx), __fmul_rn(dy, dy)),
                            __fmul_rn(dz, dz));
        k[e] = __float_as_uint(s);
    }

    int need = KK;
    unsigned prefix = 0;
    for (int l = 0; l < 4; ++l) {
        int shift = 24 - 8 * l;
        hist[t] = 0;
        __syncthreads();
        if (l == 0) {
#pragma unroll
            for (int e = 0; e < 20; ++e)
                atomicAdd(&hist[(k[e] >> 24) & 255], 1);
        } else {
            unsigned pmask = 0xFFFFFFFFu << (shift + 8);
#pragma unroll
            for (int e = 0; e < 20; ++e)
                if ((k[e] & pmask) == prefix)
                    atomicAdd(&hist[(k[e] >> shift) & 255], 1);
        }
        __syncthreads();
        int v = hist[t], c = v;
#pragma unroll
        for (int o = 1; o < 64; o <<= 1) {
            int u = __shfl_up(c, o);
            if (lane >= o) c += u;
        }
        if (lane == 63) wsum[wid] = c;
        __syncthreads();
        for (int wv = 0; wv < wid; ++wv) c += wsum[wv];
        int cex = c - v;
        if (cex < need && c >= need) { s_b = t; s_need = need - cex; }
        __syncthreads();
        prefix |= ((unsigned)s_b) << shift;
        need = s_need;
        __syncthreads();
    }

    unsigned K = prefix;     // exact threshold key
    int needK = need;        // how many ==K to take (>=1)

    if (t == 0) s_cntLess = 0;
    __syncthreads();
#pragma unroll
    for (int e = 0; e < 20; ++e) {
        if (k[e] < K) {
            int slot = atomicAdd(&s_cntLess, 1);
            if (slot < 32)
                sel[slot] = ((unsigned long long)k[e] << 32) | (unsigned)(base + e);
        }
    }
    __syncthreads();
    int nl = s_cntLess;      // == KK - needK

    if (t < nl) {
        unsigned long long mine = sel[t];
        int rk = 0;
        for (int s = 0; s < nl; ++s) rk += (sel[s] < mine);
        nb[i * KK + rk] = (int)(mine & 0xFFFFFFFFull);
    }

    unsigned tmask = 0;
#pragma unroll
    for (int e = 0; e < 20; ++e)
        if (k[e] == K) tmask |= 1u << e;

    for (int q = 0; q < needK; ++q) {
        int mi = tmask ? (base + __ffs(tmask) - 1) : 0x7fffffff;
#pragma unroll
        for (int o = 32; o; o >>= 1) mi = min(mi, __shfl_xor(mi, o));
        if (lane == 0) wmin[wid] = mi;
        __syncthreads();
        int g = min(min(wmin[0], wmin[1]), min(wmin[2], wmin[3]));
        if (t == 0) nb[i * KK + nl + q] = g;
        if (g >= base && g < base + 20) tmask &= ~(1u << (g - base));
        __syncthreads();
    }
}

// ---------------- K3: fp16 MFMA cosine screen: per-row (best, 2nd, argmax) -------
__global__ __launch_bounds__(256, 2) void k_rowmax(const __half* __restrict__ imh,
                                                   const __half* __restrict__ pch,
                                                   float* __restrict__ pval,
                                                   float* __restrict__ pv2,
                                                   int* __restrict__ pidx) {
    const __half* Ah = (blockIdx.z == 0) ? imh : pch;
    const __half* Bh = (blockIdx.z == 0) ? pch : imh;
    __shared__ char As[128 * 256];
    __shared__ char Bs[128 * 256];

    int t = threadIdx.x;
    int wave = t >> 6, l = t & 63;
    int wrow = wave >> 1, wcol = wave & 1;
    int lg = l >> 4, lc = l & 15;
    int rb = blockIdx.x * 128;
    int segbase = blockIdx.y * (NN / CSPL);

#pragma unroll
    for (int i = 0; i < 8; ++i) {
        int u = t + i * 256;
        int row = u >> 4, kb = u & 15;
        uint4 v = *(const uint4*)&Ah[(size_t)(rb + row) * CC + kb * 8];
        *(uint4*)(As + row * 256 + ((kb * 16) ^ ((row & 7) << 4))) = v;
    }

    float v1[4][4], v2[4][4]; int i1[4][4];
#pragma unroll
    for (int rt = 0; rt < 4; ++rt)
#pragma unroll
        for (int rg = 0; rg < 4; ++rg) { v1[rt][rg] = -1e30f; v2[rt][rg] = -1e30f; i1[rt][rg] = 0; }

    for (int ch = 0; ch < NN / CSPL; ch += 128) {
#pragma unroll
        for (int i = 0; i < 8; ++i) {
            int u = t + i * 256;
            int row = u >> 4, kb = u & 15;
            uint4 v = *(const uint4*)&Bh[(size_t)(segbase + ch + row) * CC + kb * 8];
            *(uint4*)(Bs + row * 256 + ((kb * 16) ^ ((row & 7) << 4))) = v;
        }
        __syncthreads();

        f32x4 acc[4][4];
#pragma unroll
        for (int rt = 0; rt < 4; ++rt)
#pragma unroll
            for (int ct = 0; ct < 4; ++ct) acc[rt][ct] = (f32x4){0.f, 0.f, 0.f, 0.f};

#pragma unroll
        for (int ks = 0; ks < 4; ++ks) {
            int kb = ks * 64 + lg * 16;
            half8 a[4], b[4];
#pragma unroll
            for (int rt = 0; rt < 4; ++rt) {
                int row = wrow * 64 + rt * 16 + lc;
                a[rt] = *(const half8*)(As + row * 256 + (kb ^ ((row & 7) << 4)));
            }
#pragma unroll
            for (int ct = 0; ct < 4; ++ct) {
                int row = wcol * 64 + ct * 16 + lc;
                b[ct] = *(const half8*)(Bs + row * 256 + (kb ^ ((row & 7) << 4)));
            }
#pragma unroll
            for (int rt = 0; rt < 4; ++rt)
#pragma unroll
                for (int ct = 0; ct < 4; ++ct)
                    acc[rt][ct] = __builtin_amdgcn_mfma_f32_16x16x32_f16(
                        a[rt], b[ct], acc[rt][ct], 0, 0, 0);
        }

        int colb = segbase + ch + wcol * 64 + lc;
#pragma unroll
        for (int rt = 0; rt < 4; ++rt)
#pragma unroll
            for (int ct = 0; ct < 4; ++ct) {
                int c = colb + ct * 16;
#pragma unroll
                for (int rg = 0; rg < 4; ++rg) {
                    float v = acc[rt][ct][rg];
                    bool gt = v > v1[rt][rg];
                    v2[rt][rg] = gt ? v1[rt][rg] : fmaxf(v2[rt][rg], v);
                    i1[rt][rg] = gt ? c : i1[rt][rg];
                    v1[rt][rg] = gt ? v : v1[rt][rg];
                }
            }
        __syncthreads();
    }

#pragma unroll
    for (int rt = 0; rt < 4; ++rt)
#pragma unroll
        for (int rg = 0; rg < 4; ++rg) {
            float a1 = v1[rt][rg], a2 = v2[rt][rg]; int ai = i1[rt][rg];
#pragma unroll
            for (int o = 1; o < 16; o <<= 1) {
                float o1 = __shfl_xor(a1, o);
                float o2v = __shfl_xor(a2, o);
                int   oi = __shfl_xor(ai, o);
                if (o1 > a1) { a2 = fmaxf(a1, o2v); a1 = o1; ai = oi; }
                else         { a2 = fmaxf(a2, o1); }
            }
            if (lc == 0) {
                int seg = blockIdx.y * 2 + wcol;
                size_t o = ((size_t)blockIdx.z * NSEG + seg) * PP
                         + rb + wrow * 64 + rt * 16 + lg * 4 + rg;
                pval[o] = a1; pv2[o] = a2; pidx[o] = ai;
            }
        }
}

// ---------------- K3b: reduce 16 partials/side, flag ambiguous rows --------------
__global__ void k_reduce_best(const float* __restrict__ pval, const float* __restrict__ pv2,
                              const int* __restrict__ pidx,
                              int* __restrict__ bestI, int* __restrict__ bestPI,
                              int* __restrict__ listA, int* __restrict__ listB,
                              int* __restrict__ cnt) {
    int r = blockIdx.x * 256 + threadIdx.x;
    int side = blockIdx.y;
    size_t base = (size_t)side * NSEG * PP + r;
    float v1 = pval[base], v2 = pv2[base]; int i1 = pidx[base];
    for (int s = 1; s < NSEG; ++s) {
        float ov1 = pval[base + (size_t)s * PP];
        float ov2 = pv2[base + (size_t)s * PP];
        int   oi  = pidx[base + (size_t)s * PP];
        if (ov1 > v1) { v2 = fmaxf(v1, ov2); v1 = ov1; i1 = oi; }
        else          { v2 = fmaxf(v2, ov1); }
    }
    if (side == 0) bestI[r] = i1; else bestPI[r] = i1;
    if (v1 - v2 < EPSG) {
        int slot = atomicAdd(&cnt[side], 1);
        (side ? listB : listA)[slot] = r;
    }
}

// ---------------- K3c: batched fp32 recheck of flagged rows (64-row tiles) -------
__global__ __launch_bounds__(256, 2) void k_recheck32(const float* __restrict__ imn,
                                                      const float* __restrict__ pcn,
                                                      const int* __restrict__ listA,
                                                      const int* __restrict__ listB,
                                                      const int* __restrict__ cnt,
                                                      float* __restrict__ q1,
                                                      float* __restrict__ q2,
                                                      int* __restrict__ qi) {
    int side = blockIdx.z, g = blockIdx.x, seg = blockIdx.y;
    int n = cnt[side];
    if (g * 64 >= n) return;
    const float* A = side ? pcn : imn;
    const float* B = side ? imn : pcn;
    const int* lst = side ? listB : listA;

    __shared__ float As[64 * CC];
    __shared__ float Bs[64 * CC];
    int t = threadIdx.x;

    for (int q = t; q < 64 * 32; q += 256) {
        int slot = q >> 5, c4 = q & 31;
        int e = g * 64 + slot;
        int r = (e < n) ? lst[e] : lst[0];
        float4 v = *(const float4*)&A[(size_t)r * CC + c4 * 4];
        int sw = ((slot >> 2) & 7) << 2;
        *(float4*)&As[slot * CC + ((c4 * 4) ^ sw)] = v;
    }

    int ty = t >> 4, tx = t & 15;
    int swA = (ty & 7) << 2;
    int swB = (tx & 7) << 2;

    float bv[4], bv2[4]; int bi[4];
#pragma unroll
    for (int ii = 0; ii < 4; ++ii) { bv[ii] = -1e30f; bv2[ii] = -1e30f; bi[ii] = 0; }

    int segBase = seg * (NN / 8);
    for (int ch = 0; ch < NN / 8; ch += 64) {
        __syncthreads();
        for (int q = t; q < 64 * 32; q += 256) {
            int row = q >> 5, c4 = q & 31;
            float4 v = *(const float4*)&B[(size_t)(segBase + ch + row) * CC + c4 * 4];
            int sw = ((row >> 2) & 7) << 2;
            *(float4*)&Bs[row * CC + ((c4 * 4) ^ sw)] = v;
        }
        __syncthreads();

        float acc[4][4];
#pragma unroll
        for (int ii = 0; ii < 4; ++ii)
#pragma unroll
            for (int jj = 0; jj < 4; ++jj) acc[ii][jj] = 0.0f;

#pragma unroll 4
        for (int cs = 0; cs < CC / 4; ++cs) {
            int c = cs << 2;
            float4 af[4], bf[4];
#pragma unroll
            for (int ii = 0; ii < 4; ++ii)
                af[ii] = *(const float4*)&As[(ty * 4 + ii) * CC + (c ^ swA)];
#pragma unroll
            for (int jj = 0; jj < 4; ++jj)
                bf[jj] = *(const float4*)&Bs[(tx * 4 + jj) * CC + (c ^ swB)];
#pragma unroll
            for (int ii = 0; ii < 4; ++ii)
#pragma unroll
                for (int jj = 0; jj < 4; ++jj) {
                    acc[ii][jj] += af[ii].x * bf[jj].x;
                    acc[ii][jj] += af[ii].y * bf[jj].y;
                    acc[ii][jj] += af[ii].z * bf[jj].z;
                    acc[ii][jj] += af[ii].w * bf[jj].w;
                }
        }

        int cb = segBase + ch + tx * 4;
#pragma unroll
        for (int ii = 0; ii < 4; ++ii)
#pragma unroll
            for (int jj = 0; jj < 4; ++jj) {
                float v = acc[ii][jj];
                if (v > bv[ii]) { bv2[ii] = bv[ii]; bv[ii] = v; bi[ii] = cb + jj; }
                else            { bv2[ii] = fmaxf(bv2[ii], v); }
            }
    }

#pragma unroll
    for (int ii = 0; ii < 4; ++ii) {
        float a1 = bv[ii], a2 = bv2[ii]; int ai = bi[ii];
#pragma unroll
        for (int o = 1; o < 16; o <<= 1) {
            float o1 = __shfl_xor(a1, o);
            float o2v = __shfl_xor(a2, o);
            int   oi = __shfl_xor(ai, o);
            if (o1 > a1) { a2 = fmaxf(a1, o2v); a1 = o1; ai = oi; }
            else         { a2 = fmaxf(a2, o1); }
        }
        if (tx == 0) {
            size_t o = ((size_t)(side * GMAX + g) * 8 + seg) * 64 + ty * 4 + ii;
            q1[o] = a1; q2[o] = a2; qi[o] = ai;
        }
    }
}

// ---------------- K3d: reduce fp32 recheck partials; funnel near-ties ------------
__global__ void k_reduce2(const float* __restrict__ q1, const float* __restrict__ q2,
                          const int* __restrict__ qi,
                          const int* __restrict__ listA, const int* __restrict__ listB,
                          int* __restrict__ cnt,
                          int* __restrict__ bestI, int* __restrict__ bestPI,
                          int* __restrict__ list2) {
    int side = blockIdx.y;
    int e = blockIdx.x * 64 + threadIdx.x;
    if (e >= cnt[side]) return;
    int g = e >> 6, slot = e & 63;
    size_t base = (size_t)(side * GMAX + g) * 8 * 64 + slot;
    float v1 = q1[base], v2 = q2[base]; int i1 = qi[base];
#pragma unroll
    for (int s = 1; s < 8; ++s) {
        float ov1 = q1[base + s * 64];
        float ov2 = q2[base + s * 64];
        int   oi  = qi[base + s * 64];
        if (ov1 > v1) { v2 = fmaxf(v1, ov2); v1 = ov1; i1 = oi; }
        else          { v2 = fmaxf(v2, ov1); }
    }
    int r = (side ? listB : listA)[e];
    if (v1 - v2 < EPS2) {
        int s2 = atomicAdd(&cnt[2], 1);
        list2[s2] = r | (side << 16);
    } else {
        if (side == 0) bestI[r] = i1; else bestPI[r] = i1;
    }
}

// ---------------- K3e: exact fp64 best VALUE for every row -----------------------
__global__ void k_exact_best(const float* __restrict__ imn, const float* __restrict__ pcn,
                             const int* __restrict__ bestI, const int* __restrict__ bestPI,
                             double* __restrict__ bestSd, double* __restrict__ bestPSd) {
    int row = blockIdx.x * 4 + (threadIdx.x >> 6);
    int lane = threadIdx.x & 63;
    const float* A; const float* B; int r; int bi;
    if (row < PP) { A = imn; B = pcn; r = row; bi = bestI[r]; }
    else          { A = pcn; B = imn; r = row - PP; bi = bestPI[r]; }
    float2 av = *(const float2*)&A[(size_t)r * CC + lane * 2];
    float2 bv = *(const float2*)&B[(size_t)bi * CC + lane * 2];
    double s = (double)av.x * (double)bv.x + (double)av.y * (double)bv.y;
#pragma unroll
    for (int o = 32; o; o >>= 1) s += __shfl_xor(s, o);
    if (lane == 0) { if (row < PP) bestSd[r] = s; else bestPSd[r] = s; }
}

// ---------------- K3f: exact fp64 repair of remaining near-ties ------------------
__global__ void k_recheck64(const float* __restrict__ imn, const float* __restrict__ pcn,
                            const int* __restrict__ list2, const int* __restrict__ cnt,
                            double* __restrict__ bestSd, int* __restrict__ bestI,
                            double* __restrict__ bestPSd, int* __restrict__ bestPI) {
    __shared__ double ad[CC];
    __shared__ double rv[4];
    __shared__ int    ri[4];
    int t = threadIdx.x;
    int wid = t >> 6, lane = t & 63;
    int total = cnt[2];
    for (int e = blockIdx.x; e < total; e += gridDim.x) {
        __syncthreads();
        int ent = list2[e];
        int r = ent & 0xffff, side = ent >> 16;
        const float* Arow = (side == 0 ? imn : pcn) + (size_t)r * CC;
        const float* B    = (side == 0 ? pcn : imn);
        if (t < CC) ad[t] = (double)Arow[t];
        __syncthreads();
        double bv = -1e300; int bi = 0x7fffffff;
        for (int j = t; j < NN; j += 256) {
            double s0 = 0.0, s1 = 0.0, s2 = 0.0, s3 = 0.0;
#pragma unroll 8
            for (int c4 = 0; c4 < CC / 4; ++c4) {
                float4 b = *(const float4*)&B[(size_t)j * CC + c4 * 4];
                s0 += ad[c4 * 4 + 0] * (double)b.x;
                s1 += ad[c4 * 4 + 1] * (double)b.y;
                s2 += ad[c4 * 4 + 2] * (double)b.z;
                s3 += ad[c4 * 4 + 3] * (double)b.w;
            }
            double s = (s0 + s1) + (s2 + s3);
            if (s > bv || (s == bv && j < bi)) { bv = s; bi = j; }
        }
#pragma unroll
        for (int o = 32; o; o >>= 1) {
            double ov = __shfl_xor(bv, o); int oi = __shfl_xor(bi, o);
            if (ov > bv || (ov == bv && oi < bi)) { bv = ov; bi = oi; }
        }
        if (lane == 0) { rv[wid] = bv; ri[wid] = bi; }
        __syncthreads();
        if (t == 0) {
            for (int wv = 1; wv < 4; ++wv)
                if (rv[wv] > bv || (rv[wv] == bv && ri[wv] < bi)) { bv = rv[wv]; bi = ri[wv]; }
            if (side == 0) { bestSd[r] = bv; bestI[r] = bi; }
            else           { bestPSd[r] = bv; bestPI[r] = bi; }
        }
    }
}

// ---------------- K4: image sim/softmax + select output + seeding ----------------
__global__ void k_im_select(const float* __restrict__ imn,
                            const double* __restrict__ bestSd,
                            const int* __restrict__ bestI,
                            float* __restrict__ outSelect,
                            int* __restrict__ seed) {
    int p = blockIdx.x * 4 + (threadIdx.x >> 6);
    int lane = threadIdx.x & 63;
    int h = p >> 7;
    int w = p & 127;
    float2 ctr = *(const float2*)&imn[p * CC + lane * 2];

    double sim[KK];
#pragma unroll
    for (int k = 0; k < KK; ++k) {
        int di = k / 5 - 2, dj = k % 5 - 2;
        int hc = min(max(h + di, 0), HH - 1);
        int wc = min(max(w + dj, 0), WW - 1);
        int q = hc * WW + wc;
        float2 nv = *(const float2*)&imn[q * CC + lane * 2];
        double part = (double)ctr.x * (double)nv.x + (double)ctr.y * (double)nv.y;
#pragma unroll
        for (int o = 32; o; o >>= 1) part += __shfl_xor(part, o);
        sim[k] = part;
    }
    double mx = sim[0];
#pragma unroll
    for (int k = 1; k < KK; ++k) mx = fmax(mx, sim[k]);
    double sum = 0.0;
#pragma unroll
    for (int k = 0; k < KK; ++k) { sim[k] = exp(sim[k] - mx); sum += sim[k]; }
    double inv = 1.0 / sum;

    double sel[KK];
#pragma unroll
    for (int k = 0; k < KK; ++k) {
        int di = k / 5 - 2, dj = k % 5 - 2;
        int h2 = h + di, w2 = w + dj;
        bool valid = (h2 >= 0 && h2 < HH && w2 >= 0 && w2 < WW);
        int hc = min(max(h2, 0), HH - 1), wc = min(max(w2, 0), WW - 1);
        double conf = bestSd[hc * WW + wc];
        double so = valid ? (sim[k] * inv * conf) : (double)NEGV;
        if (lane == k) outSelect[k * PP + p] = (float)so;
        sel[k] = (k == 12) ? (double)NEGV : so;
    }

    int tk1 = 0, tk2 = 0, tk3 = 0, tk4 = 0;
    {
        unsigned chosen = 1u << 12;
#pragma unroll
        for (int s = 0; s < 4; ++s) {
            double bvv = -1e300; int bk = 0;
#pragma unroll
            for (int k = 0; k < KK; ++k)
                if (!((chosen >> k) & 1) && sel[k] > bvv) { bvv = sel[k]; bk = k; }
            chosen |= 1u << bk;
            if (s == 0) tk1 = bk; else if (s == 1) tk2 = bk; else if (s == 2) tk3 = bk; else tk4 = bk;
        }
    }
    if (lane == 0) {
        int tks[5] = {12, tk1, tk2, tk3, tk4};
#pragma unroll
        for (int s = 0; s < 5; ++s) {
            int k = tks[s];
            int di = k / 5 - 2, dj = k % 5 - 2;
            int h2 = h + di, w2 = w + dj;
            int pix = (h2 >= 0 && h2 < HH && w2 >= 0 && w2 < WW) ? (h2 * WW + w2) : -1;
            pix = min(max(pix, 0), PP - 1);
            seed[p * SPOT + s] = bestI[pix];
        }
    }
}

// ---------------- K6: pc sim/softmax + seeding -----------------------------------
__global__ void k_pc_select(const float* __restrict__ pcn,
                            const int* __restrict__ nb,
                            const double* __restrict__ bestPSd,
                            const int* __restrict__ bestPI,
                            int* __restrict__ pcseed) {
    int i = blockIdx.x * 4 + (threadIdx.x >> 6);
    int lane = threadIdx.x & 63;
    float2 ctr = *(const float2*)&pcn[i * CC + lane * 2];

    int nbr[KK];
#pragma unroll
    for (int k = 0; k < KK; ++k) nbr[k] = nb[i * KK + k];

    double sim[KK];
#pragma unroll
    for (int k = 0; k < KK; ++k) {
        float2 nv = *(const float2*)&pcn[nbr[k] * CC + lane * 2];
        double part = (double)ctr.x * (double)nv.x + (double)ctr.y * (double)nv.y;
#pragma unroll
        for (int o = 32; o; o >>= 1) part += __shfl_xor(part, o);
        sim[k] = part;
    }
    double mx = sim[0];
#pragma unroll
    for (int k = 1; k < KK; ++k) mx = fmax(mx, sim[k]);
    double sum = 0.0;
#pragma unroll
    for (int k = 0; k < KK; ++k) { sim[k] = exp(sim[k] - mx); sum += sim[k]; }
    double inv = 1.0 / sum;

    double sel[KK];
    sel[0] = (double)NEGV;
#pragma unroll
    for (int k = 1; k < KK; ++k) sel[k] = sim[k] * inv * bestPSd[nbr[k]];

    int tk1 = 0, tk2 = 0, tk3 = 0, tk4 = 0;
    {
        unsigned chosen = 0u;
#pragma unroll
        for (int s = 0; s < 4; ++s) {
            double bvv = -1e300; int bk = 0;
#pragma unroll
            for (int k = 0; k < KK; ++k)
                if (!((chosen >> k) & 1) && sel[k] > bvv) { bvv = sel[k]; bk = k; }
            chosen |= 1u << bk;
            if (s == 0) tk1 = bk; else if (s == 1) tk2 = bk; else if (s == 2) tk3 = bk; else tk4 = bk;
        }
    }
    if (lane == 0) {
        int tks[5] = {0, tk1, tk2, tk3, tk4};
#pragma unroll
        for (int s = 0; s < 5; ++s)
            pcseed[i * SPOT + s] = bestPI[nbr[tks[s]]];
    }
}

// ---------------- bitmap -> stable top-125 compaction ----------------------------
__device__ __forceinline__ void compact_bits(const unsigned* bits, int row,
                                             float* __restrict__ maskOut,
                                             float* __restrict__ idxOut, int lane) {
    int base = 0;
    for (int w = 0; w < 160 && base < 125; ++w) {
        unsigned word = bits[w];
        int cnt = __popc(word);
        if (lane < cnt) {
            unsigned v = word;
            for (int t = 0; t < lane; ++t) v &= v - 1;
            int pos = __ffs((int)v) - 1;
            idxOut[row * 125 + base + lane]  = (float)(w * 32 + pos);
            maskOut[row * 125 + base + lane] = 1.0f;
        }
        base += cnt;
    }
    for (int w = 0; w < 160 && base < 125; ++w) {
        unsigned word = ~bits[w];
        int cnt = __popc(word);
        int take = min(cnt, 125 - base);
        if (lane < take) {
            unsigned v = word;
            for (int t = 0; t < lane; ++t) v &= v - 1;
            int pos = __ffs((int)v) - 1;
            idxOut[row * 125 + base + lane]  = (float)(w * 32 + pos);
            maskOut[row * 125 + base + lane] = 0.0f;
        }
        base += take;
    }
}

// ---------------- K5: im spoting ------------------------------------------------
__global__ void k_im_spot(const int* __restrict__ seed, const int* __restrict__ nb,
                          float* __restrict__ maskOut, float* __restrict__ idxOut) {
    __shared__ unsigned bits[4][160];
    int wid = threadIdx.x >> 6, lane = threadIdx.x & 63;
    int p = blockIdx.x * 4 + wid;
    for (int w = lane; w < 160; w += 64) bits[wid][w] = 0u;
    __syncthreads();
    for (int e = lane; e < 125; e += 64) {
        int sd = seed[p * SPOT + e / 25];
        int pt = nb[sd * KK + (e % 25)];
        atomicOr(&bits[wid][pt >> 5], 1u << (pt & 31));
    }
    __syncthreads();
    compact_bits(bits[wid], p, maskOut, idxOut, lane);
}

// ---------------- K7: pc spoting ------------------------------------------------
__global__ void k_pc_spot(const int* __restrict__ pcseed,
                          float* __restrict__ maskOut, float* __restrict__ idxOut) {
    __shared__ unsigned bits[4][160];
    int wid = threadIdx.x >> 6, lane = threadIdx.x & 63;
    int i = blockIdx.x * 4 + wid;
    for (int w = lane; w < 160; w += 64) bits[wid][w] = 0u;
    __syncthreads();
    for (int e = lane; e < 125; e += 64) {
        int q = pcseed[i * SPOT + e / 25];
        int kk = e % 25;
        int r0 = q >> 7, c0 = q & 127;
        int r = min(max(r0 + kk / 5 - 2, 0), HH - 1);
        int c = min(max(c0 + kk % 5 - 2, 0), WW - 1);
        int pix = r * WW + c;
        atomicOr(&bits[wid][pix >> 5], 1u << (pix & 31));
    }
    __syncthreads();
    compact_bits(bits[wid], i, maskOut, idxOut, lane);
}

// ---------------- host ----------------------------------------------------------
extern "C" void kernel_launch(void* const* d_in, const int* in_sizes, int n_in,
                              void* d_out, int out_size, void* d_ws, size_t ws_size,
                              hipStream_t stream) {
    const float* imf = (const float*)d_in[0];
    const float* pcf = (const float*)d_in[1];
    const float* pts = (const float*)d_in[2];
    float* out = (float*)d_out;

    char* w = (char*)d_ws;
    double* bestSd  = (double*)w;  w += (size_t)PP * 8;
    double* bestPSd = (double*)w;  w += (size_t)NN * 8;
    float*  imn     = (float*)w;   w += (size_t)PP * CC * 4;
    float*  pcn     = (float*)w;   w += (size_t)NN * CC * 4;
    __half* imh     = (__half*)w;  w += (size_t)PP * CC * 2;
    __half* pch     = (__half*)w;  w += (size_t)NN * CC * 2;
    float*  pval    = (float*)w;   w += (size_t)2 * NSEG * PP * 4;
    float*  pv2     = (float*)w;   w += (size_t)2 * NSEG * PP * 4;
    int*    pidx    = (int*)w;     w += (size_t)2 * NSEG * PP * 4;
    float*  q1      = (float*)w;   w += (size_t)2 * GMAX * 8 * 64 * 4;
    float*  q2      = (float*)w;   w += (size_t)2 * GMAX * 8 * 64 * 4;
    int*    qi      = (int*)w;     w += (size_t)2 * GMAX * 8 * 64 * 4;
    int*    nb      = (int*)w;     w += (size_t)NN * KK * 4;
    int*    bestI   = (int*)w;     w += (size_t)PP * 4;
    int*    bestPI  = (int*)w;     w += (size_t)NN * 4;
    int*    seed    = (int*)w;     w += (size_t)PP * SPOT * 4;
    int*    pcseed  = (int*)w;     w += (size_t)NN * SPOT * 4;
    int*    listA   = (int*)w;     w += (size_t)PP * 4;
    int*    listB   = (int*)w;     w += (size_t)NN * 4;
    int*    list2   = (int*)w;     w += (size_t)(PP + NN) * 4;
    int*    cnt     = (int*)w;     w += 256;

    float* outSelect = out;                       // (25, 5120)
    float* outMask   = out + KK * PP;             // (5120, 125)
    float* outIdx    = outMask + PP * 125;        // (5120, 125)
    float* outIdxPc  = outIdx + PP * 125;         // (5120, 125)
    float* outMaskPc = outIdxPc + NN * 125;       // (5120, 125)

    hipMemsetAsync(cnt, 0, 16, stream);
    k_normalize<<<(PP + NN) / 4, 256, 0, stream>>>(imf, pcf, imn, pcn, imh, pch);
    k_knn<<<NN, 256, 0, stream>>>(pts, nb);
    k_rowmax<<<dim3(PP / 128, CSPL, 2), 256, 0, stream>>>(imh, pch, pval, pv2, pidx);
    k_reduce_best<<<dim3(PP / 256, 2), 256, 0, stream>>>(pval, pv2, pidx,
                                                         bestI, bestPI, listA, listB, cnt);
    k_recheck32<<<dim3(GMAX, 8, 2), 256, 0, stream>>>(imn, pcn, listA, listB, cnt,
                                                      q1, q2, qi);
    k_reduce2<<<dim3(GMAX, 2), 64, 0, stream>>>(q1, q2, qi, listA, listB, cnt,
                                                bestI, bestPI, list2);
    k_exact_best<<<2 * PP / 4, 256, 0, stream>>>(imn, pcn, bestI, bestPI, bestSd, bestPSd);
    k_recheck64<<<256, 256, 0, stream>>>(imn, pcn, list2, cnt,
                                         bestSd, bestI, bestPSd, bestPI);
    k_im_select<<<PP / 4, 256, 0, stream>>>(imn, bestSd, bestI, outSelect, seed);
    k_pc_select<<<NN / 4, 256, 0, stream>>>(pcn, nb, bestPSd, bestPI, pcseed);
    k_im_spot<<<PP / 4, 256, 0, stream>>>(seed, nb, outMask, outIdx);
    k_pc_spot<<<NN / 4, 256, 0, stream>>>(pcseed, outMaskPc, outIdxPc);
}

// Round 8
// 451.004 us; speedup vs baseline: 1.4144x; 1.0075x over previous
//
#include <hip/hip_runtime.h>
#include <hip/hip_fp16.h>
#include <float.h>
#include <math.h>

#define HH 40
#define WW 128
#define PP 5120
#define NN 5120
#define CC 128
#define KK 25
#define SPOT 5
#define NEGV -1e8f

#define CSPL 8          // column segments for the MFMA screen (x2 wcol halves = 16 partials)
#define NSEG 16
#define EPSG 3e-3f      // fp16 screen gap threshold; sound bound 1.98e-3, 1.5x margin
#define EPS2 1e-4f      // fp32 recheck gap threshold; sound bound 7.6e-6, 13x margin

#define RR   32         // fp32 recheck: rows per group
#define RSEG 32         // fp32 recheck: column segments (160 cols each)
#define RGM  64         // fp32 recheck: max groups/side (2048 rows); overflow -> fp64 path

typedef _Float16 half8 __attribute__((ext_vector_type(8)));
typedef float f32x4 __attribute__((ext_vector_type(4)));

// ---------------- K1: L2-normalize rows (fp64 norm; fp32 + fp16 copies) ----------
__global__ void k_normalize(const float* __restrict__ imf, const float* __restrict__ pcf,
                            float* __restrict__ imn, float* __restrict__ pcn,
                            __half* __restrict__ imh, __half* __restrict__ pch) {
    int row = blockIdx.x * 4 + (threadIdx.x >> 6);
    int lane = threadIdx.x & 63;
    const float* src; float* dst; __half* dsth; int r;
    if (row < PP) { src = imf; dst = imn; dsth = imh; r = row; }
    else          { src = pcf; dst = pcn; dsth = pch; r = row - PP; }
    float2 v = *(const float2*)&src[r * CC + lane * 2];
    double ss = (double)v.x * (double)v.x + (double)v.y * (double)v.y;
#pragma unroll
    for (int o = 32; o; o >>= 1) ss += __shfl_xor(ss, o);
    double inv = 1.0 / fmax(sqrt(ss), 1e-12);
    float2 o2 = make_float2((float)((double)v.x * inv), (float)((double)v.y * inv));
    *(float2*)&dst[r * CC + lane * 2] = o2;
    *(__half2*)&dsth[r * CC + lane * 2] = __floats2half2_rn(o2.x, o2.y);
}

// ---------------- K2: KNN top-25 via 8-bit radix-select on fp32 keys -------------
__global__ __launch_bounds__(256) void k_knn(const float* __restrict__ pts,
                                             int* __restrict__ nb) {
    __shared__ int hist[256];
    __shared__ int wsum[4];
    __shared__ int wmin[4];
    __shared__ int s_b, s_need, s_cntLess;
    __shared__ unsigned long long sel[32];
    int i = blockIdx.x, t = threadIdx.x;
    int wid = t >> 6, lane = t & 63;
    float px = pts[i * 3 + 0], py = pts[i * 3 + 1], pz = pts[i * 3 + 2];

    unsigned k[20];
    int base = t * 20;
#pragma unroll
    for (int e = 0; e < 20; ++e) {
        int j = base + e;
        float dx = __fsub_rn(px, pts[j * 3 + 0]);
        float dy = __fsub_rn(py, pts[j * 3 + 1]);
        float dz = __fsub_rn(pz, pts[j * 3 + 2]);
        float s = __fadd_rn(__fadd_rn(__fmul_rn(dx, dx), __fmul_rn(dy, dy)),
                            __fmul_rn(dz, dz));
        k[e] = __float_as_uint(s);
    }

    int need = KK;
    unsigned prefix = 0;
    for (int l = 0; l < 4; ++l) {
        int shift = 24 - 8 * l;
        hist[t] = 0;
        __syncthreads();
        if (l == 0) {
#pragma unroll
            for (int e = 0; e < 20; ++e)
                atomicAdd(&hist[(k[e] >> 24) & 255], 1);
        } else {
            unsigned pmask = 0xFFFFFFFFu << (shift + 8);
#pragma unroll
            for (int e = 0; e < 20; ++e)
                if ((k[e] & pmask) == prefix)
                    atomicAdd(&hist[(k[e] >> shift) & 255], 1);
        }
        __syncthreads();
        int v = hist[t], c = v;
#pragma unroll
        for (int o = 1; o < 64; o <<= 1) {
            int u = __shfl_up(c, o);
            if (lane >= o) c += u;
        }
        if (lane == 63) wsum[wid] = c;
        __syncthreads();
        for (int wv = 0; wv < wid; ++wv) c += wsum[wv];
        int cex = c - v;
        if (cex < need && c >= need) { s_b = t; s_need = need - cex; }
        __syncthreads();
        prefix |= ((unsigned)s_b) << shift;
        need = s_need;
        __syncthreads();
    }

    unsigned K = prefix;
    int needK = need;

    if (t == 0) s_cntLess = 0;
    __syncthreads();
#pragma unroll
    for (int e = 0; e < 20; ++e) {
        if (k[e] < K) {
            int slot = atomicAdd(&s_cntLess, 1);
            if (slot < 32)
                sel[slot] = ((unsigned long long)k[e] << 32) | (unsigned)(base + e);
        }
    }
    __syncthreads();
    int nl = s_cntLess;

    if (t < nl) {
        unsigned long long mine = sel[t];
        int rk = 0;
        for (int s = 0; s < nl; ++s) rk += (sel[s] < mine);
        nb[i * KK + rk] = (int)(mine & 0xFFFFFFFFull);
    }

    unsigned tmask = 0;
#pragma unroll
    for (int e = 0; e < 20; ++e)
        if (k[e] == K) tmask |= 1u << e;

    for (int q = 0; q < needK; ++q) {
        int mi = tmask ? (base + __ffs(tmask) - 1) : 0x7fffffff;
#pragma unroll
        for (int o = 32; o; o >>= 1) mi = min(mi, __shfl_xor(mi, o));
        if (lane == 0) wmin[wid] = mi;
        __syncthreads();
        int g = min(min(wmin[0], wmin[1]), min(wmin[2], wmin[3]));
        if (t == 0) nb[i * KK + nl + q] = g;
        if (g >= base && g < base + 20) tmask &= ~(1u << (g - base));
        __syncthreads();
    }
}

// ---------------- K3: fp16 MFMA cosine screen: per-row (best, 2nd, argmax) -------
__global__ __launch_bounds__(256, 2) void k_rowmax(const __half* __restrict__ imh,
                                                   const __half* __restrict__ pch,
                                                   float* __restrict__ pval,
                                                   float* __restrict__ pv2,
                                                   int* __restrict__ pidx) {
    const __half* Ah = (blockIdx.z == 0) ? imh : pch;
    const __half* Bh = (blockIdx.z == 0) ? pch : imh;
    __shared__ char As[128 * 256];
    __shared__ char Bs[128 * 256];

    int t = threadIdx.x;
    int wave = t >> 6, l = t & 63;
    int wrow = wave >> 1, wcol = wave & 1;
    int lg = l >> 4, lc = l & 15;
    int rb = blockIdx.x * 128;
    int segbase = blockIdx.y * (NN / CSPL);

#pragma unroll
    for (int i = 0; i < 8; ++i) {
        int u = t + i * 256;
        int row = u >> 4, kb = u & 15;
        uint4 v = *(const uint4*)&Ah[(size_t)(rb + row) * CC + kb * 8];
        *(uint4*)(As + row * 256 + ((kb * 16) ^ ((row & 7) << 4))) = v;
    }

    float v1[4][4], v2[4][4]; int i1[4][4];
#pragma unroll
    for (int rt = 0; rt < 4; ++rt)
#pragma unroll
        for (int rg = 0; rg < 4; ++rg) { v1[rt][rg] = -1e30f; v2[rt][rg] = -1e30f; i1[rt][rg] = 0; }

    for (int ch = 0; ch < NN / CSPL; ch += 128) {
#pragma unroll
        for (int i = 0; i < 8; ++i) {
            int u = t + i * 256;
            int row = u >> 4, kb = u & 15;
            uint4 v = *(const uint4*)&Bh[(size_t)(segbase + ch + row) * CC + kb * 8];
            *(uint4*)(Bs + row * 256 + ((kb * 16) ^ ((row & 7) << 4))) = v;
        }
        __syncthreads();

        f32x4 acc[4][4];
#pragma unroll
        for (int rt = 0; rt < 4; ++rt)
#pragma unroll
            for (int ct = 0; ct < 4; ++ct) acc[rt][ct] = (f32x4){0.f, 0.f, 0.f, 0.f};

#pragma unroll
        for (int ks = 0; ks < 4; ++ks) {
            int kb = ks * 64 + lg * 16;
            half8 a[4], b[4];
#pragma unroll
            for (int rt = 0; rt < 4; ++rt) {
                int row = wrow * 64 + rt * 16 + lc;
                a[rt] = *(const half8*)(As + row * 256 + (kb ^ ((row & 7) << 4)));
            }
#pragma unroll
            for (int ct = 0; ct < 4; ++ct) {
                int row = wcol * 64 + ct * 16 + lc;
                b[ct] = *(const half8*)(Bs + row * 256 + (kb ^ ((row & 7) << 4)));
            }
#pragma unroll
            for (int rt = 0; rt < 4; ++rt)
#pragma unroll
                for (int ct = 0; ct < 4; ++ct)
                    acc[rt][ct] = __builtin_amdgcn_mfma_f32_16x16x32_f16(
                        a[rt], b[ct], acc[rt][ct], 0, 0, 0);
        }

        int colb = segbase + ch + wcol * 64 + lc;
#pragma unroll
        for (int rt = 0; rt < 4; ++rt)
#pragma unroll
            for (int ct = 0; ct < 4; ++ct) {
                int c = colb + ct * 16;
#pragma unroll
                for (int rg = 0; rg < 4; ++rg) {
                    float v = acc[rt][ct][rg];
                    bool gt = v > v1[rt][rg];
                    v2[rt][rg] = gt ? v1[rt][rg] : fmaxf(v2[rt][rg], v);
                    i1[rt][rg] = gt ? c : i1[rt][rg];
                    v1[rt][rg] = gt ? v : v1[rt][rg];
                }
            }
        __syncthreads();
    }

#pragma unroll
    for (int rt = 0; rt < 4; ++rt)
#pragma unroll
        for (int rg = 0; rg < 4; ++rg) {
            float a1 = v1[rt][rg], a2 = v2[rt][rg]; int ai = i1[rt][rg];
#pragma unroll
            for (int o = 1; o < 16; o <<= 1) {
                float o1 = __shfl_xor(a1, o);
                float o2v = __shfl_xor(a2, o);
                int   oi = __shfl_xor(ai, o);
                if (o1 > a1) { a2 = fmaxf(a1, o2v); a1 = o1; ai = oi; }
                else         { a2 = fmaxf(a2, o1); }
            }
            if (lc == 0) {
                int seg = blockIdx.y * 2 + wcol;
                size_t o = ((size_t)blockIdx.z * NSEG + seg) * PP
                         + rb + wrow * 64 + rt * 16 + lg * 4 + rg;
                pval[o] = a1; pv2[o] = a2; pidx[o] = ai;
            }
        }
}

// ---------------- K3b: reduce 16 partials/side, flag ambiguous rows --------------
// Overflow beyond RGM*RR flagged rows per side goes straight to the fp64 path.
__global__ void k_reduce_best(const float* __restrict__ pval, const float* __restrict__ pv2,
                              const int* __restrict__ pidx,
                              int* __restrict__ bestI, int* __restrict__ bestPI,
                              int* __restrict__ listA, int* __restrict__ listB,
                              int* __restrict__ list2, int* __restrict__ cnt) {
    int r = blockIdx.x * 256 + threadIdx.x;
    int side = blockIdx.y;
    size_t base = (size_t)side * NSEG * PP + r;
    float v1 = pval[base], v2 = pv2[base]; int i1 = pidx[base];
    for (int s = 1; s < NSEG; ++s) {
        float ov1 = pval[base + (size_t)s * PP];
        float ov2 = pv2[base + (size_t)s * PP];
        int   oi  = pidx[base + (size_t)s * PP];
        if (ov1 > v1) { v2 = fmaxf(v1, ov2); v1 = ov1; i1 = oi; }
        else          { v2 = fmaxf(v2, ov1); }
    }
    if (side == 0) bestI[r] = i1; else bestPI[r] = i1;
    if (v1 - v2 < EPSG) {
        int slot = atomicAdd(&cnt[side], 1);
        if (slot < RGM * RR) (side ? listB : listA)[slot] = r;
        else { int s2 = atomicAdd(&cnt[2], 1); list2[s2] = r | (side << 16); }
    }
}

// ---------------- K3c: batched fp32 recheck (32-row groups x 32 col-segments) ----
// grid (RGM, RSEG, 2); 32 KB LDS -> 4 blocks/CU; 2x2 per-thread tiles.
__global__ __launch_bounds__(256, 4) void k_recheck32(const float* __restrict__ imn,
                                                      const float* __restrict__ pcn,
                                                      const int* __restrict__ listA,
                                                      const int* __restrict__ listB,
                                                      const int* __restrict__ cnt,
                                                      float* __restrict__ q1,
                                                      float* __restrict__ q2,
                                                      int* __restrict__ qi) {
    int side = blockIdx.z, g = blockIdx.x, seg = blockIdx.y;
    int n = min(cnt[side], RGM * RR);
    if (g * RR >= n) return;
    const float* A = side ? pcn : imn;
    const float* B = side ? imn : pcn;
    const int* lst = side ? listB : listA;

    __shared__ float As[RR * CC];   // 16 KB
    __shared__ float Bs[RR * CC];   // 16 KB (32-col chunk)
    int t = threadIdx.x;

    for (int q = t; q < RR * 32; q += 256) {
        int slot = q >> 5, c4 = q & 31;
        int e = g * RR + slot;
        int r = (e < n) ? lst[e] : lst[0];
        float4 v = *(const float4*)&A[(size_t)r * CC + c4 * 4];
        int sw = ((slot >> 2) & 7) << 2;
        *(float4*)&As[slot * CC + ((c4 * 4) ^ sw)] = v;
    }

    int ty = t >> 4, tx = t & 15;   // 16x2 rows, 16x2 cols

    float bv[2][2], bv2[2][2]; int bi[2][2];
#pragma unroll
    for (int ii = 0; ii < 2; ++ii)
#pragma unroll
        for (int jj = 0; jj < 2; ++jj) { bv[ii][jj] = -1e30f; bv2[ii][jj] = -1e30f; bi[ii][jj] = 0; }

    int segBase = seg * (NN / RSEG);            // 160 cols/segment
    for (int ch = 0; ch < NN / RSEG; ch += RR) { // 5 chunks of 32
        __syncthreads();
        for (int q = t; q < RR * 32; q += 256) {
            int row = q >> 5, c4 = q & 31;
            float4 v = *(const float4*)&B[(size_t)(segBase + ch + row) * CC + c4 * 4];
            int sw = ((row >> 2) & 7) << 2;
            *(float4*)&Bs[row * CC + ((c4 * 4) ^ sw)] = v;
        }
        __syncthreads();

        float acc[2][2];
#pragma unroll
        for (int ii = 0; ii < 2; ++ii)
#pragma unroll
            for (int jj = 0; jj < 2; ++jj) acc[ii][jj] = 0.0f;

#pragma unroll 4
        for (int cs = 0; cs < CC / 4; ++cs) {
            int c = cs << 2;
            float4 af[2], bf[2];
#pragma unroll
            for (int ii = 0; ii < 2; ++ii) {
                int row = ty * 2 + ii;
                af[ii] = *(const float4*)&As[row * CC + (c ^ (((row >> 2) & 7) << 2))];
            }
#pragma unroll
            for (int jj = 0; jj < 2; ++jj) {
                int row = tx * 2 + jj;
                bf[jj] = *(const float4*)&Bs[row * CC + (c ^ (((row >> 2) & 7) << 2))];
            }
#pragma unroll
            for (int ii = 0; ii < 2; ++ii)
#pragma unroll
                for (int jj = 0; jj < 2; ++jj) {
                    acc[ii][jj] += af[ii].x * bf[jj].x;
                    acc[ii][jj] += af[ii].y * bf[jj].y;
                    acc[ii][jj] += af[ii].z * bf[jj].z;
                    acc[ii][jj] += af[ii].w * bf[jj].w;
                }
        }

        int cb = segBase + ch + tx * 2;
#pragma unroll
        for (int ii = 0; ii < 2; ++ii)
#pragma unroll
            for (int jj = 0; jj < 2; ++jj) {
                float v = acc[ii][jj];
                if (v > bv[ii][jj]) { bv2[ii][jj] = bv[ii][jj]; bv[ii][jj] = v; bi[ii][jj] = cb + jj; }
                else                { bv2[ii][jj] = fmaxf(bv2[ii][jj], v); }
            }
    }

#pragma unroll
    for (int ii = 0; ii < 2; ++ii) {
        // combine the two per-thread columns (col0 wins ties: strict >)
        float a1, a2; int ai;
        if (bv[ii][1] > bv[ii][0]) { a1 = bv[ii][1]; a2 = fmaxf(bv[ii][0], bv2[ii][1]); ai = bi[ii][1]; }
        else                       { a1 = bv[ii][0]; a2 = fmaxf(bv[ii][1], bv2[ii][0]); ai = bi[ii][0]; }
#pragma unroll
        for (int o = 1; o < 16; o <<= 1) {
            float o1 = __shfl_xor(a1, o);
            float o2v = __shfl_xor(a2, o);
            int   oi = __shfl_xor(ai, o);
            if (o1 > a1) { a2 = fmaxf(a1, o2v); a1 = o1; ai = oi; }
            else         { a2 = fmaxf(a2, o1); }
        }
        if (tx == 0) {
            size_t o = ((size_t)(side * RGM + g) * RSEG + seg) * RR + ty * 2 + ii;
            q1[o] = a1; q2[o] = a2; qi[o] = ai;
        }
    }
}

// ---------------- K3d: reduce fp32 recheck partials; funnel near-ties ------------
__global__ void k_reduce2(const float* __restrict__ q1, const float* __restrict__ q2,
                          const int* __restrict__ qi,
                          const int* __restrict__ listA, const int* __restrict__ listB,
                          int* __restrict__ cnt,
                          int* __restrict__ bestI, int* __restrict__ bestPI,
                          int* __restrict__ list2) {
    int side = blockIdx.y;
    int e = blockIdx.x * 64 + threadIdx.x;
    int n = min(cnt[side], RGM * RR);
    if (e >= n) return;
    int g = e >> 5, slot = e & 31;
    size_t base = ((size_t)(side * RGM + g) * RSEG) * RR + slot;
    float v1 = q1[base], v2 = q2[base]; int i1 = qi[base];
#pragma unroll 4
    for (int s = 1; s < RSEG; ++s) {
        float ov1 = q1[base + (size_t)s * RR];
        float ov2 = q2[base + (size_t)s * RR];
        int   oi  = qi[base + (size_t)s * RR];
        if (ov1 > v1) { v2 = fmaxf(v1, ov2); v1 = ov1; i1 = oi; }
        else          { v2 = fmaxf(v2, ov1); }
    }
    int r = (side ? listB : listA)[e];
    if (v1 - v2 < EPS2) {
        int s2 = atomicAdd(&cnt[2], 1);
        list2[s2] = r | (side << 16);
    } else {
        if (side == 0) bestI[r] = i1; else bestPI[r] = i1;
    }
}

// ---------------- K3e: exact fp64 best VALUE for every row -----------------------
__global__ void k_exact_best(const float* __restrict__ imn, const float* __restrict__ pcn,
                             const int* __restrict__ bestI, const int* __restrict__ bestPI,
                             double* __restrict__ bestSd, double* __restrict__ bestPSd) {
    int row = blockIdx.x * 4 + (threadIdx.x >> 6);
    int lane = threadIdx.x & 63;
    const float* A; const float* B; int r; int bi;
    if (row < PP) { A = imn; B = pcn; r = row; bi = bestI[r]; }
    else          { A = pcn; B = imn; r = row - PP; bi = bestPI[r]; }
    float2 av = *(const float2*)&A[(size_t)r * CC + lane * 2];
    float2 bv = *(const float2*)&B[(size_t)bi * CC + lane * 2];
    double s = (double)av.x * (double)bv.x + (double)av.y * (double)bv.y;
#pragma unroll
    for (int o = 32; o; o >>= 1) s += __shfl_xor(s, o);
    if (lane == 0) { if (row < PP) bestSd[r] = s; else bestPSd[r] = s; }
}

// ---------------- K3f: exact fp64 repair of remaining near-ties ------------------
__global__ void k_recheck64(const float* __restrict__ imn, const float* __restrict__ pcn,
                            const int* __restrict__ list2, const int* __restrict__ cnt,
                            double* __restrict__ bestSd, int* __restrict__ bestI,
                            double* __restrict__ bestPSd, int* __restrict__ bestPI) {
    __shared__ double ad[CC];
    __shared__ double rv[4];
    __shared__ int    ri[4];
    int t = threadIdx.x;
    int wid = t >> 6, lane = t & 63;
    int total = cnt[2];
    for (int e = blockIdx.x; e < total; e += gridDim.x) {
        __syncthreads();
        int ent = list2[e];
        int r = ent & 0xffff, side = ent >> 16;
        const float* Arow = (side == 0 ? imn : pcn) + (size_t)r * CC;
        const float* B    = (side == 0 ? pcn : imn);
        if (t < CC) ad[t] = (double)Arow[t];
        __syncthreads();
        double bv = -1e300; int bi = 0x7fffffff;
        for (int j = t; j < NN; j += 256) {
            double s0 = 0.0, s1 = 0.0, s2 = 0.0, s3 = 0.0;
#pragma unroll 8
            for (int c4 = 0; c4 < CC / 4; ++c4) {
                float4 b = *(const float4*)&B[(size_t)j * CC + c4 * 4];
                s0 += ad[c4 * 4 + 0] * (double)b.x;
                s1 += ad[c4 * 4 + 1] * (double)b.y;
                s2 += ad[c4 * 4 + 2] * (double)b.z;
                s3 += ad[c4 * 4 + 3] * (double)b.w;
            }
            double s = (s0 + s1) + (s2 + s3);
            if (s > bv || (s == bv && j < bi)) { bv = s; bi = j; }
        }
#pragma unroll
        for (int o = 32; o; o >>= 1) {
            double ov = __shfl_xor(bv, o); int oi = __shfl_xor(bi, o);
            if (ov > bv || (ov == bv && oi < bi)) { bv = ov; bi = oi; }
        }
        if (lane == 0) { rv[wid] = bv; ri[wid] = bi; }
        __syncthreads();
        if (t == 0) {
            for (int wv = 1; wv < 4; ++wv)
                if (rv[wv] > bv || (rv[wv] == bv && ri[wv] < bi)) { bv = rv[wv]; bi = ri[wv]; }
            if (side == 0) { bestSd[r] = bv; bestI[r] = bi; }
            else           { bestPSd[r] = bv; bestPI[r] = bi; }
        }
    }
}

// ---------------- K4: image sim/softmax + select output + seeding ----------------
__global__ void k_im_select(const float* __restrict__ imn,
                            const double* __restrict__ bestSd,
                            const int* __restrict__ bestI,
                            float* __restrict__ outSelect,
                            int* __restrict__ seed) {
    int p = blockIdx.x * 4 + (threadIdx.x >> 6);
    int lane = threadIdx.x & 63;
    int h = p >> 7;
    int w = p & 127;
    float2 ctr = *(const float2*)&imn[p * CC + lane * 2];

    double sim[KK];
#pragma unroll
    for (int k = 0; k < KK; ++k) {
        int di = k / 5 - 2, dj = k % 5 - 2;
        int hc = min(max(h + di, 0), HH - 1);
        int wc = min(max(w + dj, 0), WW - 1);
        int q = hc * WW + wc;
        float2 nv = *(const float2*)&imn[q * CC + lane * 2];
        double part = (double)ctr.x * (double)nv.x + (double)ctr.y * (double)nv.y;
#pragma unroll
        for (int o = 32; o; o >>= 1) part += __shfl_xor(part, o);
        sim[k] = part;
    }
    double mx = sim[0];
#pragma unroll
    for (int k = 1; k < KK; ++k) mx = fmax(mx, sim[k]);
    double sum = 0.0;
#pragma unroll
    for (int k = 0; k < KK; ++k) { sim[k] = exp(sim[k] - mx); sum += sim[k]; }
    double inv = 1.0 / sum;

    double sel[KK];
#pragma unroll
    for (int k = 0; k < KK; ++k) {
        int di = k / 5 - 2, dj = k % 5 - 2;
        int h2 = h + di, w2 = w + dj;
        bool valid = (h2 >= 0 && h2 < HH && w2 >= 0 && w2 < WW);
        int hc = min(max(h2, 0), HH - 1), wc = min(max(w2, 0), WW - 1);
        double conf = bestSd[hc * WW + wc];
        double so = valid ? (sim[k] * inv * conf) : (double)NEGV;
        if (lane == k) outSelect[k * PP + p] = (float)so;
        sel[k] = (k == 12) ? (double)NEGV : so;
    }

    int tk1 = 0, tk2 = 0, tk3 = 0, tk4 = 0;
    {
        unsigned chosen = 1u << 12;
#pragma unroll
        for (int s = 0; s < 4; ++s) {
            double bvv = -1e300; int bk = 0;
#pragma unroll
            for (int k = 0; k < KK; ++k)
                if (!((chosen >> k) & 1) && sel[k] > bvv) { bvv = sel[k]; bk = k; }
            chosen |= 1u << bk;
            if (s == 0) tk1 = bk; else if (s == 1) tk2 = bk; else if (s == 2) tk3 = bk; else tk4 = bk;
        }
    }
    if (lane == 0) {
        int tks[5] = {12, tk1, tk2, tk3, tk4};
#pragma unroll
        for (int s = 0; s < 5; ++s) {
            int k = tks[s];
            int di = k / 5 - 2, dj = k % 5 - 2;
            int h2 = h + di, w2 = w + dj;
            int pix = (h2 >= 0 && h2 < HH && w2 >= 0 && w2 < WW) ? (h2 * WW + w2) : -1;
            pix = min(max(pix, 0), PP - 1);
            seed[p * SPOT + s] = bestI[pix];
        }
    }
}

// ---------------- K6: pc sim/softmax + seeding -----------------------------------
__global__ void k_pc_select(const float* __restrict__ pcn,
                            const int* __restrict__ nb,
                            const double* __restrict__ bestPSd,
                            const int* __restrict__ bestPI,
                            int* __restrict__ pcseed) {
    int i = blockIdx.x * 4 + (threadIdx.x >> 6);
    int lane = threadIdx.x & 63;
    float2 ctr = *(const float2*)&pcn[i * CC + lane * 2];

    int nbr[KK];
#pragma unroll
    for (int k = 0; k < KK; ++k) nbr[k] = nb[i * KK + k];

    double sim[KK];
#pragma unroll
    for (int k = 0; k < KK; ++k) {
        float2 nv = *(const float2*)&pcn[nbr[k] * CC + lane * 2];
        double part = (double)ctr.x * (double)nv.x + (double)ctr.y * (double)nv.y;
#pragma unroll
        for (int o = 32; o; o >>= 1) part += __shfl_xor(part, o);
        sim[k] = part;
    }
    double mx = sim[0];
#pragma unroll
    for (int k = 1; k < KK; ++k) mx = fmax(mx, sim[k]);
    double sum = 0.0;
#pragma unroll
    for (int k = 0; k < KK; ++k) { sim[k] = exp(sim[k] - mx); sum += sim[k]; }
    double inv = 1.0 / sum;

    double sel[KK];
    sel[0] = (double)NEGV;
#pragma unroll
    for (int k = 1; k < KK; ++k) sel[k] = sim[k] * inv * bestPSd[nbr[k]];

    int tk1 = 0, tk2 = 0, tk3 = 0, tk4 = 0;
    {
        unsigned chosen = 0u;
#pragma unroll
        for (int s = 0; s < 4; ++s) {
            double bvv = -1e300; int bk = 0;
#pragma unroll
            for (int k = 0; k < KK; ++k)
                if (!((chosen >> k) & 1) && sel[k] > bvv) { bvv = sel[k]; bk = k; }
            chosen |= 1u << bk;
            if (s == 0) tk1 = bk; else if (s == 1) tk2 = bk; else if (s == 2) tk3 = bk; else tk4 = bk;
        }
    }
    if (lane == 0) {
        int tks[5] = {0, tk1, tk2, tk3, tk4};
#pragma unroll
        for (int s = 0; s < 5; ++s)
            pcseed[i * SPOT + s] = bestPI[nbr[tks[s]]];
    }
}

// ---------------- bitmap -> stable top-125 compaction ----------------------------
__device__ __forceinline__ void compact_bits(const unsigned* bits, int row,
                                             float* __restrict__ maskOut,
                                             float* __restrict__ idxOut, int lane) {
    int base = 0;
    for (int w = 0; w < 160 && base < 125; ++w) {
        unsigned word = bits[w];
        int cnt = __popc(word);
        if (lane < cnt) {
            unsigned v = word;
            for (int t = 0; t < lane; ++t) v &= v - 1;
            int pos = __ffs((int)v) - 1;
            idxOut[row * 125 + base + lane]  = (float)(w * 32 + pos);
            maskOut[row * 125 + base + lane] = 1.0f;
        }
        base += cnt;
    }
    for (int w = 0; w < 160 && base < 125; ++w) {
        unsigned word = ~bits[w];
        int cnt = __popc(word);
        int take = min(cnt, 125 - base);
        if (lane < take) {
            unsigned v = word;
            for (int t = 0; t < lane; ++t) v &= v - 1;
            int pos = __ffs((int)v) - 1;
            idxOut[row * 125 + base + lane]  = (float)(w * 32 + pos);
            maskOut[row * 125 + base + lane] = 0.0f;
        }
        base += take;
    }
}

// ---------------- K5: im spoting ------------------------------------------------
__global__ void k_im_spot(const int* __restrict__ seed, const int* __restrict__ nb,
                          float* __restrict__ maskOut, float* __restrict__ idxOut) {
    __shared__ unsigned bits[4][160];
    int wid = threadIdx.x >> 6, lane = threadIdx.x & 63;
    int p = blockIdx.x * 4 + wid;
    for (int w = lane; w < 160; w += 64) bits[wid][w] = 0u;
    __syncthreads();
    for (int e = lane; e < 125; e += 64) {
        int sd = seed[p * SPOT + e / 25];
        int pt = nb[sd * KK + (e % 25)];
        atomicOr(&bits[wid][pt >> 5], 1u << (pt & 31));
    }
    __syncthreads();
    compact_bits(bits[wid], p, maskOut, idxOut, lane);
}

// ---------------- K7: pc spoting ------------------------------------------------
__global__ void k_pc_spot(const int* __restrict__ pcseed,
                          float* __restrict__ maskOut, float* __restrict__ idxOut) {
    __shared__ unsigned bits[4][160];
    int wid = threadIdx.x >> 6, lane = threadIdx.x & 63;
    int i = blockIdx.x * 4 + wid;
    for (int w = lane; w < 160; w += 64) bits[wid][w] = 0u;
    __syncthreads();
    for (int e = lane; e < 125; e += 64) {
        int q = pcseed[i * SPOT + e / 25];
        int kk = e % 25;
        int r0 = q >> 7, c0 = q & 127;
        int r = min(max(r0 + kk / 5 - 2, 0), HH - 1);
        int c = min(max(c0 + kk % 5 - 2, 0), WW - 1);
        int pix = r * WW + c;
        atomicOr(&bits[wid][pix >> 5], 1u << (pix & 31));
    }
    __syncthreads();
    compact_bits(bits[wid], i, maskOut, idxOut, lane);
}

// ---------------- host ----------------------------------------------------------
extern "C" void kernel_launch(void* const* d_in, const int* in_sizes, int n_in,
                              void* d_out, int out_size, void* d_ws, size_t ws_size,
                              hipStream_t stream) {
    const float* imf = (const float*)d_in[0];
    const float* pcf = (const float*)d_in[1];
    const float* pts = (const float*)d_in[2];
    float* out = (float*)d_out;

    char* w = (char*)d_ws;
    double* bestSd  = (double*)w;  w += (size_t)PP * 8;
    double* bestPSd = (double*)w;  w += (size_t)NN * 8;
    float*  imn     = (float*)w;   w += (size_t)PP * CC * 4;
    float*  pcn     = (float*)w;   w += (size_t)NN * CC * 4;
    __half* imh     = (__half*)w;  w += (size_t)PP * CC * 2;
    __half* pch     = (__half*)w;  w += (size_t)NN * CC * 2;
    float*  pval    = (float*)w;   w += (size_t)2 * NSEG * PP * 4;
    float*  pv2     = (float*)w;   w += (size_t)2 * NSEG * PP * 4;
    int*    pidx    = (int*)w;     w += (size_t)2 * NSEG * PP * 4;
    float*  q1      = (float*)w;   w += (size_t)2 * RGM * RSEG * RR * 4;
    float*  q2      = (float*)w;   w += (size_t)2 * RGM * RSEG * RR * 4;
    int*    qi      = (int*)w;     w += (size_t)2 * RGM * RSEG * RR * 4;
    int*    nb      = (int*)w;     w += (size_t)NN * KK * 4;
    int*    bestI   = (int*)w;     w += (size_t)PP * 4;
    int*    bestPI  = (int*)w;     w += (size_t)NN * 4;
    int*    seed    = (int*)w;     w += (size_t)PP * SPOT * 4;
    int*    pcseed  = (int*)w;     w += (size_t)NN * SPOT * 4;
    int*    listA   = (int*)w;     w += (size_t)PP * 4;
    int*    listB   = (int*)w;     w += (size_t)NN * 4;
    int*    list2   = (int*)w;     w += (size_t)(PP + NN) * 4;
    int*    cnt     = (int*)w;     w += 256;

    float* outSelect = out;                       // (25, 5120)
    float* outMask   = out + KK * PP;             // (5120, 125)
    float* outIdx    = outMask + PP * 125;        // (5120, 125)
    float* outIdxPc  = outIdx + PP * 125;         // (5120, 125)
    float* outMaskPc = outIdxPc + NN * 125;       // (5120, 125)

    hipMemsetAsync(cnt, 0, 16, stream);
    k_normalize<<<(PP + NN) / 4, 256, 0, stream>>>(imf, pcf, imn, pcn, imh, pch);
    k_knn<<<NN, 256, 0, stream>>>(pts, nb);
    k_rowmax<<<dim3(PP / 128, CSPL, 2), 256, 0, stream>>>(imh, pch, pval, pv2, pidx);
    k_reduce_best<<<dim3(PP / 256, 2), 256, 0, stream>>>(pval, pv2, pidx,
                                                         bestI, bestPI, listA, listB,
                                                         list2, cnt);
    k_recheck32<<<dim3(RGM, RSEG, 2), 256, 0, stream>>>(imn, pcn, listA, listB, cnt,
                                                        q1, q2, qi);
    k_reduce2<<<dim3(RGM * RR / 64, 2), 64, 0, stream>>>(q1, q2, qi, listA, listB, cnt,
                                                         bestI, bestPI, list2);
    k_exact_best<<<2 * PP / 4, 256, 0, stream>>>(imn, pcn, bestI, bestPI, bestSd, bestPSd);
    k_recheck64<<<256, 256, 0, stream>>>(imn, pcn, list2, cnt,
                                         bestSd, bestI, bestPSd, bestPI);
    k_im_select<<<PP / 4, 256, 0, stream>>>(imn, bestSd, bestI, outSelect, seed);
    k_pc_select<<<NN / 4, 256, 0, stream>>>(pcn, nb, bestPSd, bestPI, pcseed);
    k_im_spot<<<PP / 4, 256, 0, stream>>>(seed, nb, outMask, outIdx);
    k_pc_spot<<<NN / 4, 256, 0, stream>>>(pcseed, outMaskPc, outIdxPc);
}

// Round 9
// 379.422 us; speedup vs baseline: 1.6812x; 1.1887x over previous
//
#include <hip/hip_runtime.h>
#include <hip/hip_fp16.h>
#include <float.h>
#include <math.h>

#define HH 40
#define WW 128
#define PP 5120
#define NN 5120
#define CC 128
#define KK 25
#define SPOT 5
#define NEGV -1e8f

#define CSPL 8          // column segments for the split-fp16 screen
#define NSEG 16         // partials per side = CSPL x 2 wave col-halves
#define EPS  1e-4f      // screen gap threshold; split-fp16 error bound ~3e-6, 33x margin
#define LOSC 2048.0f    // lo-term scale (2^11) keeps lo in fp16 normal range

typedef _Float16 half8 __attribute__((ext_vector_type(8)));
typedef float f32x4 __attribute__((ext_vector_type(4)));

// ---------------- K1: L2-normalize rows (fp64 norm; fp32 + split-fp16 copies) ----
__global__ void k_normalize(const float* __restrict__ imf, const float* __restrict__ pcf,
                            float* __restrict__ imn, float* __restrict__ pcn,
                            __half* __restrict__ imh, __half* __restrict__ iml,
                            __half* __restrict__ pch, __half* __restrict__ pcl) {
    int row = blockIdx.x * 4 + (threadIdx.x >> 6);
    int lane = threadIdx.x & 63;
    const float* src; float* dst; __half* dh; __half* dl; int r;
    if (row < PP) { src = imf; dst = imn; dh = imh; dl = iml; r = row; }
    else          { src = pcf; dst = pcn; dh = pch; dl = pcl; r = row - PP; }
    float2 v = *(const float2*)&src[r * CC + lane * 2];
    double ss = (double)v.x * (double)v.x + (double)v.y * (double)v.y;
#pragma unroll
    for (int o = 32; o; o >>= 1) ss += __shfl_xor(ss, o);
    double inv = 1.0 / fmax(sqrt(ss), 1e-12);
    float2 o2 = make_float2((float)((double)v.x * inv), (float)((double)v.y * inv));
    *(float2*)&dst[r * CC + lane * 2] = o2;
    __half hx = __float2half_rn(o2.x), hy = __float2half_rn(o2.y);
    float rx = o2.x - __half2float(hx), ry = o2.y - __half2float(hy);
    __half2 hh; hh.x = hx; hh.y = hy;
    __half2 ll; ll.x = __float2half_rn(rx * LOSC); ll.y = __float2half_rn(ry * LOSC);
    *(__half2*)&dh[r * CC + lane * 2] = hh;
    *(__half2*)&dl[r * CC + lane * 2] = ll;
}

// ---------------- K2: KNN top-25 via 8-bit radix-select on fp32 keys -------------
__global__ __launch_bounds__(256) void k_knn(const float* __restrict__ pts,
                                             int* __restrict__ nb) {
    __shared__ int hist[256];
    __shared__ int wsum[4];
    __shared__ int wmin[4];
    __shared__ int s_b, s_need, s_cntLess;
    __shared__ unsigned long long sel[32];
    int i = blockIdx.x, t = threadIdx.x;
    int wid = t >> 6, lane = t & 63;
    float px = pts[i * 3 + 0], py = pts[i * 3 + 1], pz = pts[i * 3 + 2];

    unsigned k[20];
    int base = t * 20;
#pragma unroll
    for (int e = 0; e < 20; ++e) {
        int j = base + e;
        float dx = __fsub_rn(px, pts[j * 3 + 0]);
        float dy = __fsub_rn(py, pts[j * 3 + 1]);
        float dz = __fsub_rn(pz, pts[j * 3 + 2]);
        float s = __fadd_rn(__fadd_rn(__fmul_rn(dx, dx), __fmul_rn(dy, dy)),
                            __fmul_rn(dz, dz));
        k[e] = __float_as_uint(s);
    }

    int need = KK;
    unsigned prefix = 0;
    for (int l = 0; l < 4; ++l) {
        int shift = 24 - 8 * l;
        hist[t] = 0;
        __syncthreads();
        if (l == 0) {
#pragma unroll
            for (int e = 0; e < 20; ++e)
                atomicAdd(&hist[(k[e] >> 24) & 255], 1);
        } else {
            unsigned pmask = 0xFFFFFFFFu << (shift + 8);
#pragma unroll
            for (int e = 0; e < 20; ++e)
                if ((k[e] & pmask) == prefix)
                    atomicAdd(&hist[(k[e] >> shift) & 255], 1);
        }
        __syncthreads();
        int v = hist[t], c = v;
#pragma unroll
        for (int o = 1; o < 64; o <<= 1) {
            int u = __shfl_up(c, o);
            if (lane >= o) c += u;
        }
        if (lane == 63) wsum[wid] = c;
        __syncthreads();
        for (int wv = 0; wv < wid; ++wv) c += wsum[wv];
        int cex = c - v;
        if (cex < need && c >= need) { s_b = t; s_need = need - cex; }
        __syncthreads();
        prefix |= ((unsigned)s_b) << shift;
        need = s_need;
        __syncthreads();
    }

    unsigned K = prefix;
    int needK = need;

    if (t == 0) s_cntLess = 0;
    __syncthreads();
#pragma unroll
    for (int e = 0; e < 20; ++e) {
        if (k[e] < K) {
            int slot = atomicAdd(&s_cntLess, 1);
            if (slot < 32)
                sel[slot] = ((unsigned long long)k[e] << 32) | (unsigned)(base + e);
        }
    }
    __syncthreads();
    int nl = s_cntLess;

    if (t < nl) {
        unsigned long long mine = sel[t];
        int rk = 0;
        for (int s = 0; s < nl; ++s) rk += (sel[s] < mine);
        nb[i * KK + rk] = (int)(mine & 0xFFFFFFFFull);
    }

    unsigned tmask = 0;
#pragma unroll
    for (int e = 0; e < 20; ++e)
        if (k[e] == K) tmask |= 1u << e;

    for (int q = 0; q < needK; ++q) {
        int mi = tmask ? (base + __ffs(tmask) - 1) : 0x7fffffff;
#pragma unroll
        for (int o = 32; o; o >>= 1) mi = min(mi, __shfl_xor(mi, o));
        if (lane == 0) wmin[wid] = mi;
        __syncthreads();
        int g = min(min(wmin[0], wmin[1]), min(wmin[2], wmin[3]));
        if (t == 0) nb[i * KK + nl + q] = g;
        if (g >= base && g < base + 20) tmask &= ~(1u << (g - base));
        __syncthreads();
    }
}

// ---------------- K3: split-fp16 MFMA cosine screen (error ~3e-6) ----------------
// dot = hi.hi + (hi.lo + lo.hi)/2048; lo.lo dropped (<=2^-22). Block: 64 A-rows x
// 640-col segment, chunks of 64; 4 waves as 2x2; per wave 32x32 via 2x2 MFMA tiles
// x3 MFMA (hi*hi into accH; hi*lo + lo*hi into accX). Per-row (best,2nd,argmax);
// gap < EPS -> exact fp64 repair.
__global__ __launch_bounds__(256, 2) void k_rowmax(const __half* __restrict__ imh,
                                                   const __half* __restrict__ iml,
                                                   const __half* __restrict__ pch,
                                                   const __half* __restrict__ pcl,
                                                   float* __restrict__ pval,
                                                   float* __restrict__ pv2,
                                                   int* __restrict__ pidx) {
    const __half* Ah = (blockIdx.z == 0) ? imh : pch;
    const __half* Al = (blockIdx.z == 0) ? iml : pcl;
    const __half* Bh = (blockIdx.z == 0) ? pch : imh;
    const __half* Bl = (blockIdx.z == 0) ? pcl : iml;
    __shared__ char sAh[64 * 256];
    __shared__ char sAl[64 * 256];
    __shared__ char sBh[64 * 256];
    __shared__ char sBl[64 * 256];

    int t = threadIdx.x;
    int wave = t >> 6, l = t & 63;
    int wrow = wave >> 1, wcol = wave & 1;
    int lg = l >> 4, lc = l & 15;
    int rb = blockIdx.x * 64;
    const int segLen = NN / CSPL;               // 640
    int segbase = blockIdx.y * segLen;

    // stage A (hi + lo), swizzled
#pragma unroll
    for (int i = 0; i < 4; ++i) {
        int u = t + i * 256;
        int row = u >> 4, kb = u & 15;
        int off = row * 256 + ((kb * 16) ^ ((row & 7) << 4));
        *(uint4*)(sAh + off) = *(const uint4*)&Ah[(size_t)(rb + row) * CC + kb * 8];
        *(uint4*)(sAl + off) = *(const uint4*)&Al[(size_t)(rb + row) * CC + kb * 8];
    }

    float v1[2][2][4], v2[2][2][4]; int i1[2][2][4];
#pragma unroll
    for (int rt = 0; rt < 2; ++rt)
#pragma unroll
        for (int ct = 0; ct < 2; ++ct)
#pragma unroll
            for (int rg = 0; rg < 4; ++rg) {
                v1[rt][ct][rg] = -1e30f; v2[rt][ct][rg] = -1e30f; i1[rt][ct][rg] = 0;
            }

    for (int ch = 0; ch < segLen; ch += 64) {
#pragma unroll
        for (int i = 0; i < 4; ++i) {
            int u = t + i * 256;
            int row = u >> 4, kb = u & 15;
            int off = row * 256 + ((kb * 16) ^ ((row & 7) << 4));
            *(uint4*)(sBh + off) = *(const uint4*)&Bh[(size_t)(segbase + ch + row) * CC + kb * 8];
            *(uint4*)(sBl + off) = *(const uint4*)&Bl[(size_t)(segbase + ch + row) * CC + kb * 8];
        }
        __syncthreads();

        f32x4 aH[2][2], aX[2][2];
#pragma unroll
        for (int rt = 0; rt < 2; ++rt)
#pragma unroll
            for (int ct = 0; ct < 2; ++ct) {
                aH[rt][ct] = (f32x4){0.f, 0.f, 0.f, 0.f};
                aX[rt][ct] = (f32x4){0.f, 0.f, 0.f, 0.f};
            }

#pragma unroll
        for (int ks = 0; ks < 4; ++ks) {
            int kb = ks * 64 + lg * 16;
            half8 ah[2], al[2], bh[2], bl[2];
#pragma unroll
            for (int rt = 0; rt < 2; ++rt) {
                int row = wrow * 32 + rt * 16 + lc;
                int off = row * 256 + (kb ^ ((row & 7) << 4));
                ah[rt] = *(const half8*)(sAh + off);
                al[rt] = *(const half8*)(sAl + off);
            }
#pragma unroll
            for (int ct = 0; ct < 2; ++ct) {
                int row = wcol * 32 + ct * 16 + lc;
                int off = row * 256 + (kb ^ ((row & 7) << 4));
                bh[ct] = *(const half8*)(sBh + off);
                bl[ct] = *(const half8*)(sBl + off);
            }
#pragma unroll
            for (int rt = 0; rt < 2; ++rt)
#pragma unroll
                for (int ct = 0; ct < 2; ++ct) {
                    aH[rt][ct] = __builtin_amdgcn_mfma_f32_16x16x32_f16(
                        ah[rt], bh[ct], aH[rt][ct], 0, 0, 0);
                    aX[rt][ct] = __builtin_amdgcn_mfma_f32_16x16x32_f16(
                        ah[rt], bl[ct], aX[rt][ct], 0, 0, 0);
                    aX[rt][ct] = __builtin_amdgcn_mfma_f32_16x16x32_f16(
                        al[rt], bh[ct], aX[rt][ct], 0, 0, 0);
                }
        }

#pragma unroll
        for (int rt = 0; rt < 2; ++rt)
#pragma unroll
            for (int ct = 0; ct < 2; ++ct) {
                int c = segbase + ch + wcol * 32 + ct * 16 + lc;
#pragma unroll
                for (int rg = 0; rg < 4; ++rg) {
                    float v = aH[rt][ct][rg] + aX[rt][ct][rg] * (1.0f / LOSC);
                    bool gt = v > v1[rt][ct][rg];
                    v2[rt][ct][rg] = gt ? v1[rt][ct][rg] : fmaxf(v2[rt][ct][rg], v);
                    i1[rt][ct][rg] = gt ? c : i1[rt][ct][rg];
                    v1[rt][ct][rg] = gt ? v : v1[rt][ct][rg];
                }
            }
        __syncthreads();
    }

    // fold the two ct-tiles, then merge across 16 col-lanes
#pragma unroll
    for (int rt = 0; rt < 2; ++rt)
#pragma unroll
        for (int rg = 0; rg < 4; ++rg) {
            float a1, a2; int ai;
            {
                float x1 = v1[rt][0][rg], x2 = v2[rt][0][rg]; int xi = i1[rt][0][rg];
                float y1 = v1[rt][1][rg], y2 = v2[rt][1][rg]; int yi = i1[rt][1][rg];
                if (y1 > x1) { a1 = y1; a2 = fmaxf(x1, y2); ai = yi; }
                else         { a1 = x1; a2 = fmaxf(y1, x2); ai = xi; }
            }
#pragma unroll
            for (int o = 1; o < 16; o <<= 1) {
                float o1 = __shfl_xor(a1, o);
                float o2v = __shfl_xor(a2, o);
                int   oi = __shfl_xor(ai, o);
                if (o1 > a1) { a2 = fmaxf(a1, o2v); a1 = o1; ai = oi; }
                else         { a2 = fmaxf(a2, o1); }
            }
            if (lc == 0) {
                int seg = blockIdx.y * 2 + wcol;
                size_t o = ((size_t)blockIdx.z * NSEG + seg) * PP
                         + rb + wrow * 32 + rt * 16 + lg * 4 + rg;
                pval[o] = a1; pv2[o] = a2; pidx[o] = ai;
            }
        }
}

// ---------------- K3b: reduce 16 partials/side; near-ties -> fp64 list -----------
__global__ void k_reduce_best(const float* __restrict__ pval, const float* __restrict__ pv2,
                              const int* __restrict__ pidx,
                              int* __restrict__ bestI, int* __restrict__ bestPI,
                              int* __restrict__ list2, int* __restrict__ cnt) {
    int r = blockIdx.x * 256 + threadIdx.x;
    int side = blockIdx.y;
    size_t base = (size_t)side * NSEG * PP + r;
    float v1 = pval[base], v2 = pv2[base]; int i1 = pidx[base];
    for (int s = 1; s < NSEG; ++s) {
        float ov1 = pval[base + (size_t)s * PP];
        float ov2 = pv2[base + (size_t)s * PP];
        int   oi  = pidx[base + (size_t)s * PP];
        if (ov1 > v1) { v2 = fmaxf(v1, ov2); v1 = ov1; i1 = oi; }
        else          { v2 = fmaxf(v2, ov1); }
    }
    if (side == 0) bestI[r] = i1; else bestPI[r] = i1;
    if (v1 - v2 < EPS) {
        int slot = atomicAdd(&cnt[0], 1);
        list2[slot] = r | (side << 16);
    }
}

// ---------------- K3e: exact fp64 best VALUE for every row -----------------------
__global__ void k_exact_best(const float* __restrict__ imn, const float* __restrict__ pcn,
                             const int* __restrict__ bestI, const int* __restrict__ bestPI,
                             double* __restrict__ bestSd, double* __restrict__ bestPSd) {
    int row = blockIdx.x * 4 + (threadIdx.x >> 6);
    int lane = threadIdx.x & 63;
    const float* A; const float* B; int r; int bi;
    if (row < PP) { A = imn; B = pcn; r = row; bi = bestI[r]; }
    else          { A = pcn; B = imn; r = row - PP; bi = bestPI[r]; }
    float2 av = *(const float2*)&A[(size_t)r * CC + lane * 2];
    float2 bv = *(const float2*)&B[(size_t)bi * CC + lane * 2];
    double s = (double)av.x * (double)bv.x + (double)av.y * (double)bv.y;
#pragma unroll
    for (int o = 32; o; o >>= 1) s += __shfl_xor(s, o);
    if (lane == 0) { if (row < PP) bestSd[r] = s; else bestPSd[r] = s; }
}

// ---------------- K3f: exact fp64 repair of flagged near-ties --------------------
__global__ void k_recheck64(const float* __restrict__ imn, const float* __restrict__ pcn,
                            const int* __restrict__ list2, const int* __restrict__ cnt,
                            double* __restrict__ bestSd, int* __restrict__ bestI,
                            double* __restrict__ bestPSd, int* __restrict__ bestPI) {
    __shared__ double ad[CC];
    __shared__ double rv[4];
    __shared__ int    ri[4];
    int t = threadIdx.x;
    int wid = t >> 6, lane = t & 63;
    int total = cnt[0];
    for (int e = blockIdx.x; e < total; e += gridDim.x) {
        __syncthreads();
        int ent = list2[e];
        int r = ent & 0xffff, side = ent >> 16;
        const float* Arow = (side == 0 ? imn : pcn) + (size_t)r * CC;
        const float* B    = (side == 0 ? pcn : imn);
        if (t < CC) ad[t] = (double)Arow[t];
        __syncthreads();
        double bv = -1e300; int bi = 0x7fffffff;
        for (int j = t; j < NN; j += 256) {
            double s0 = 0.0, s1 = 0.0, s2 = 0.0, s3 = 0.0;
#pragma unroll 8
            for (int c4 = 0; c4 < CC / 4; ++c4) {
                float4 b = *(const float4*)&B[(size_t)j * CC + c4 * 4];
                s0 += ad[c4 * 4 + 0] * (double)b.x;
                s1 += ad[c4 * 4 + 1] * (double)b.y;
                s2 += ad[c4 * 4 + 2] * (double)b.z;
                s3 += ad[c4 * 4 + 3] * (double)b.w;
            }
            double s = (s0 + s1) + (s2 + s3);
            if (s > bv || (s == bv && j < bi)) { bv = s; bi = j; }
        }
#pragma unroll
        for (int o = 32; o; o >>= 1) {
            double ov = __shfl_xor(bv, o); int oi = __shfl_xor(bi, o);
            if (ov > bv || (ov == bv && oi < bi)) { bv = ov; bi = oi; }
        }
        if (lane == 0) { rv[wid] = bv; ri[wid] = bi; }
        __syncthreads();
        if (t == 0) {
            for (int wv = 1; wv < 4; ++wv)
                if (rv[wv] > bv || (rv[wv] == bv && ri[wv] < bi)) { bv = rv[wv]; bi = ri[wv]; }
            if (side == 0) { bestSd[r] = bv; bestI[r] = bi; }
            else           { bestPSd[r] = bv; bestPI[r] = bi; }
        }
    }
}

// ---------------- K4: image sim/softmax + select output + seeding ----------------
__global__ void k_im_select(const float* __restrict__ imn,
                            const double* __restrict__ bestSd,
                            const int* __restrict__ bestI,
                            float* __restrict__ outSelect,
                            int* __restrict__ seed) {
    int p = blockIdx.x * 4 + (threadIdx.x >> 6);
    int lane = threadIdx.x & 63;
    int h = p >> 7;
    int w = p & 127;
    float2 ctr = *(const float2*)&imn[p * CC + lane * 2];

    double sim[KK];
#pragma unroll
    for (int k = 0; k < KK; ++k) {
        int di = k / 5 - 2, dj = k % 5 - 2;
        int hc = min(max(h + di, 0), HH - 1);
        int wc = min(max(w + dj, 0), WW - 1);
        int q = hc * WW + wc;
        float2 nv = *(const float2*)&imn[q * CC + lane * 2];
        double part = (double)ctr.x * (double)nv.x + (double)ctr.y * (double)nv.y;
#pragma unroll
        for (int o = 32; o; o >>= 1) part += __shfl_xor(part, o);
        sim[k] = part;
    }
    double mx = sim[0];
#pragma unroll
    for (int k = 1; k < KK; ++k) mx = fmax(mx, sim[k]);
    double sum = 0.0;
#pragma unroll
    for (int k = 0; k < KK; ++k) { sim[k] = exp(sim[k] - mx); sum += sim[k]; }
    double inv = 1.0 / sum;

    double sel[KK];
#pragma unroll
    for (int k = 0; k < KK; ++k) {
        int di = k / 5 - 2, dj = k % 5 - 2;
        int h2 = h + di, w2 = w + dj;
        bool valid = (h2 >= 0 && h2 < HH && w2 >= 0 && w2 < WW);
        int hc = min(max(h2, 0), HH - 1), wc = min(max(w2, 0), WW - 1);
        double conf = bestSd[hc * WW + wc];
        double so = valid ? (sim[k] * inv * conf) : (double)NEGV;
        if (lane == k) outSelect[k * PP + p] = (float)so;
        sel[k] = (k == 12) ? (double)NEGV : so;
    }

    int tk1 = 0, tk2 = 0, tk3 = 0, tk4 = 0;
    {
        unsigned chosen = 1u << 12;
#pragma unroll
        for (int s = 0; s < 4; ++s) {
            double bvv = -1e300; int bk = 0;
#pragma unroll
            for (int k = 0; k < KK; ++k)
                if (!((chosen >> k) & 1) && sel[k] > bvv) { bvv = sel[k]; bk = k; }
            chosen |= 1u << bk;
            if (s == 0) tk1 = bk; else if (s == 1) tk2 = bk; else if (s == 2) tk3 = bk; else tk4 = bk;
        }
    }
    if (lane == 0) {
        int tks[5] = {12, tk1, tk2, tk3, tk4};
#pragma unroll
        for (int s = 0; s < 5; ++s) {
            int k = tks[s];
            int di = k / 5 - 2, dj = k % 5 - 2;
            int h2 = h + di, w2 = w + dj;
            int pix = (h2 >= 0 && h2 < HH && w2 >= 0 && w2 < WW) ? (h2 * WW + w2) : -1;
            pix = min(max(pix, 0), PP - 1);
            seed[p * SPOT + s] = bestI[pix];
        }
    }
}

// ---------------- K6: pc sim/softmax + seeding -----------------------------------
__global__ void k_pc_select(const float* __restrict__ pcn,
                            const int* __restrict__ nb,
                            const double* __restrict__ bestPSd,
                            const int* __restrict__ bestPI,
                            int* __restrict__ pcseed) {
    int i = blockIdx.x * 4 + (threadIdx.x >> 6);
    int lane = threadIdx.x & 63;
    float2 ctr = *(const float2*)&pcn[i * CC + lane * 2];

    int nbr[KK];
#pragma unroll
    for (int k = 0; k < KK; ++k) nbr[k] = nb[i * KK + k];

    double sim[KK];
#pragma unroll
    for (int k = 0; k < KK; ++k) {
        float2 nv = *(const float2*)&pcn[nbr[k] * CC + lane * 2];
        double part = (double)ctr.x * (double)nv.x + (double)ctr.y * (double)nv.y;
#pragma unroll
        for (int o = 32; o; o >>= 1) part += __shfl_xor(part, o);
        sim[k] = part;
    }
    double mx = sim[0];
#pragma unroll
    for (int k = 1; k < KK; ++k) mx = fmax(mx, sim[k]);
    double sum = 0.0;
#pragma unroll
    for (int k = 0; k < KK; ++k) { sim[k] = exp(sim[k] - mx); sum += sim[k]; }
    double inv = 1.0 / sum;

    double sel[KK];
    sel[0] = (double)NEGV;
#pragma unroll
    for (int k = 1; k < KK; ++k) sel[k] = sim[k] * inv * bestPSd[nbr[k]];

    int tk1 = 0, tk2 = 0, tk3 = 0, tk4 = 0;
    {
        unsigned chosen = 0u;
#pragma unroll
        for (int s = 0; s < 4; ++s) {
            double bvv = -1e300; int bk = 0;
#pragma unroll
            for (int k = 0; k < KK; ++k)
                if (!((chosen >> k) & 1) && sel[k] > bvv) { bvv = sel[k]; bk = k; }
            chosen |= 1u << bk;
            if (s == 0) tk1 = bk; else if (s == 1) tk2 = bk; else if (s == 2) tk3 = bk; else tk4 = bk;
        }
    }
    if (lane == 0) {
        int tks[5] = {0, tk1, tk2, tk3, tk4};
#pragma unroll
        for (int s = 0; s < 5; ++s)
            pcseed[i * SPOT + s] = bestPI[nbr[tks[s]]];
    }
}

// ---------------- bitmap -> stable top-125 compaction ----------------------------
__device__ __forceinline__ void compact_bits(const unsigned* bits, int row,
                                             float* __restrict__ maskOut,
                                             float* __restrict__ idxOut, int lane) {
    int base = 0;
    for (int w = 0; w < 160 && base < 125; ++w) {
        unsigned word = bits[w];
        int cnt = __popc(word);
        if (lane < cnt) {
            unsigned v = word;
            for (int t = 0; t < lane; ++t) v &= v - 1;
            int pos = __ffs((int)v) - 1;
            idxOut[row * 125 + base + lane]  = (float)(w * 32 + pos);
            maskOut[row * 125 + base + lane] = 1.0f;
        }
        base += cnt;
    }
    for (int w = 0; w < 160 && base < 125; ++w) {
        unsigned word = ~bits[w];
        int cnt = __popc(word);
        int take = min(cnt, 125 - base);
        if (lane < take) {
            unsigned v = word;
            for (int t = 0; t < lane; ++t) v &= v - 1;
            int pos = __ffs((int)v) - 1;
            idxOut[row * 125 + base + lane]  = (float)(w * 32 + pos);
            maskOut[row * 125 + base + lane] = 0.0f;
        }
        base += take;
    }
}

// ---------------- K5: im spoting ------------------------------------------------
__global__ void k_im_spot(const int* __restrict__ seed, const int* __restrict__ nb,
                          float* __restrict__ maskOut, float* __restrict__ idxOut) {
    __shared__ unsigned bits[4][160];
    int wid = threadIdx.x >> 6, lane = threadIdx.x & 63;
    int p = blockIdx.x * 4 + wid;
    for (int w = lane; w < 160; w += 64) bits[wid][w] = 0u;
    __syncthreads();
    for (int e = lane; e < 125; e += 64) {
        int sd = seed[p * SPOT + e / 25];
        int pt = nb[sd * KK + (e % 25)];
        atomicOr(&bits[wid][pt >> 5], 1u << (pt & 31));
    }
    __syncthreads();
    compact_bits(bits[wid], p, maskOut, idxOut, lane);
}

// ---------------- K7: pc spoting ------------------------------------------------
__global__ void k_pc_spot(const int* __restrict__ pcseed,
                          float* __restrict__ maskOut, float* __restrict__ idxOut) {
    __shared__ unsigned bits[4][160];
    int wid = threadIdx.x >> 6, lane = threadIdx.x & 63;
    int i = blockIdx.x * 4 + wid;
    for (int w = lane; w < 160; w += 64) bits[wid][w] = 0u;
    __syncthreads();
    for (int e = lane; e < 125; e += 64) {
        int q = pcseed[i * SPOT + e / 25];
        int kk = e % 25;
        int r0 = q >> 7, c0 = q & 127;
        int r = min(max(r0 + kk / 5 - 2, 0), HH - 1);
        int c = min(max(c0 + kk % 5 - 2, 0), WW - 1);
        int pix = r * WW + c;
        atomicOr(&bits[wid][pix >> 5], 1u << (pix & 31));
    }
    __syncthreads();
    compact_bits(bits[wid], i, maskOut, idxOut, lane);
}

// ---------------- host ----------------------------------------------------------
extern "C" void kernel_launch(void* const* d_in, const int* in_sizes, int n_in,
                              void* d_out, int out_size, void* d_ws, size_t ws_size,
                              hipStream_t stream) {
    const float* imf = (const float*)d_in[0];
    const float* pcf = (const float*)d_in[1];
    const float* pts = (const float*)d_in[2];
    float* out = (float*)d_out;

    char* w = (char*)d_ws;
    double* bestSd  = (double*)w;  w += (size_t)PP * 8;
    double* bestPSd = (double*)w;  w += (size_t)NN * 8;
    float*  imn     = (float*)w;   w += (size_t)PP * CC * 4;
    float*  pcn     = (float*)w;   w += (size_t)NN * CC * 4;
    __half* imh     = (__half*)w;  w += (size_t)PP * CC * 2;
    __half* iml     = (__half*)w;  w += (size_t)PP * CC * 2;
    __half* pch     = (__half*)w;  w += (size_t)NN * CC * 2;
    __half* pcl     = (__half*)w;  w += (size_t)NN * CC * 2;
    float*  pval    = (float*)w;   w += (size_t)2 * NSEG * PP * 4;
    float*  pv2     = (float*)w;   w += (size_t)2 * NSEG * PP * 4;
    int*    pidx    = (int*)w;     w += (size_t)2 * NSEG * PP * 4;
    int*    nb      = (int*)w;     w += (size_t)NN * KK * 4;
    int*    bestI   = (int*)w;     w += (size_t)PP * 4;
    int*    bestPI  = (int*)w;     w += (size_t)NN * 4;
    int*    seed    = (int*)w;     w += (size_t)PP * SPOT * 4;
    int*    pcseed  = (int*)w;     w += (size_t)NN * SPOT * 4;
    int*    list2   = (int*)w;     w += (size_t)(PP + NN) * 4;
    int*    cnt     = (int*)w;     w += 256;

    float* outSelect = out;                       // (25, 5120)
    float* outMask   = out + KK * PP;             // (5120, 125)
    float* outIdx    = outMask + PP * 125;        // (5120, 125)
    float* outIdxPc  = outIdx + PP * 125;         // (5120, 125)
    float* outMaskPc = outIdxPc + NN * 125;       // (5120, 125)

    hipMemsetAsync(cnt, 0, 16, stream);
    k_normalize<<<(PP + NN) / 4, 256, 0, stream>>>(imf, pcf, imn, pcn,
                                                   imh, iml, pch, pcl);
    k_knn<<<NN, 256, 0, stream>>>(pts, nb);
    k_rowmax<<<dim3(PP / 64, CSPL, 2), 256, 0, stream>>>(imh, iml, pch, pcl,
                                                         pval, pv2, pidx);
    k_reduce_best<<<dim3(PP / 256, 2), 256, 0, stream>>>(pval, pv2, pidx,
                                                         bestI, bestPI, list2, cnt);
    k_exact_best<<<2 * PP / 4, 256, 0, stream>>>(imn, pcn, bestI, bestPI, bestSd, bestPSd);
    k_recheck64<<<256, 256, 0, stream>>>(imn, pcn, list2, cnt,
                                         bestSd, bestI, bestPSd, bestPI);
    k_im_select<<<PP / 4, 256, 0, stream>>>(imn, bestSd, bestI, outSelect, seed);
    k_pc_select<<<NN / 4, 256, 0, stream>>>(pcn, nb, bestPSd, bestPI, pcseed);
    k_im_spot<<<PP / 4, 256, 0, stream>>>(seed, nb, outMask, outIdx);
    k_pc_spot<<<NN / 4, 256, 0, stream>>>(pcseed, outMaskPc, outIdxPc);
}